// Round 13
// baseline (401.764 us; speedup 1.0000x reference)
//
#include <hip/hip_runtime.h>
#include <hip/hip_bf16.h>
#include <math.h>

// Problem constants
#define BSZ 8
#define LSEQ 512
#define ENC_IN 7
#define D_MODEL 768
#define D_INNER 1536
#define DT_RANK 48
#define N_STATE 16
#define K_CONV 4
#define E_LAYERS 2
#define C_OUT 7
#define PRED_LEN 96
#define EPSV 1e-5f
#define XN 80
#define KSPLIT 4

#define ROWS (BSZ*LSEQ)            // 4096
#define NC 16                      // scan chunks
#define CL (LSEQ/NC)               // 32 steps per chunk
#define NTILE (LSEQ/16)            // 32 16-step tiles per batch
#define LOG2E 1.44269504088896f

typedef __bf16 bf16x8 __attribute__((ext_vector_type(8)));
typedef float  f32x4  __attribute__((ext_vector_type(4)));

// raw hardware exp2 (single v_exp_f32)
__device__ __forceinline__ float fexp2(float x) {
    float r;
    asm("v_exp_f32 %0, %1" : "=v"(r) : "v"(x));
    return r;
}
__device__ __forceinline__ float softplusf(float v) {
    return fmaxf(v, 0.f) + log1pf(__expf(-fabsf(v)));
}
__device__ __forceinline__ void glds16(const char* g, char* l) {
    __builtin_amdgcn_global_load_lds((const __attribute__((address_space(1))) unsigned int*)g,
                                     (__attribute__((address_space(3))) unsigned int*)l, 16, 0, 0);
}

// ---------------------------------------------------------------- utilities
__device__ __forceinline__ float block_sum(float v, float* tmp) {
    #pragma unroll
    for (int off = 32; off > 0; off >>= 1) v += __shfl_down(v, off);
    int lane = threadIdx.x & 63, wid = threadIdx.x >> 6;
    __syncthreads();
    if (lane == 0) tmp[wid] = v;
    __syncthreads();
    return tmp[0] + tmp[1] + tmp[2] + tmp[3];
}

// ---------------------------------------------------------------- fused weight conversion (one launch)
__global__ __launch_bounds__(256) void cvt_all(const float* __restrict__ in_w,
                                               const float* __restrict__ outw,
                                               const float* __restrict__ xpw,
                                               const float* __restrict__ dtw,
                                               __hip_bfloat16* __restrict__ inw_bf,
                                               __hip_bfloat16* __restrict__ outw_bf,
                                               __hip_bfloat16* __restrict__ xpw_bf,
                                               __hip_bfloat16* __restrict__ dtw_bf) {
    const int N1 = E_LAYERS*2*D_INNER*D_MODEL;
    const int N2 = E_LAYERS*D_MODEL*D_INNER;
    const int N3 = E_LAYERS*XN*D_INNER;
    const int N4 = E_LAYERS*D_INNER*64;
    int i = blockIdx.x*256 + threadIdx.x;
    if (i < N1) {
        inw_bf[i] = __float2bfloat16(in_w[i]);
    } else if (i < N1+N2) {
        int j = i - N1; outw_bf[j] = __float2bfloat16(outw[j]);
    } else if (i < N1+N2+N3) {
        int j = i - N1 - N2; xpw_bf[j] = __float2bfloat16(xpw[j]);
    } else if (i < N1+N2+N3+N4) {
        int j = i - N1 - N2 - N3;
        int r = j >> 6, c = j & 63;
        dtw_bf[j] = __float2bfloat16(c < DT_RANK ? dtw[r*DT_RANK + c] : 0.f);
    }
}

// ---------------------------------------------------------------- stats (RevIN)
__global__ __launch_bounds__(256) void stats_kernel(const float* __restrict__ x,
                                                    float* __restrict__ mean,
                                                    float* __restrict__ stdv) {
    int bc = blockIdx.x;
    int b = bc / ENC_IN, c = bc % ENC_IN;
    __shared__ float tmp[4];
    float s = 0.f, sq = 0.f;
    for (int l = threadIdx.x; l < LSEQ; l += 256) {
        float v = x[((size_t)(b*LSEQ + l))*ENC_IN + c];
        s += v; sq += v*v;
    }
    s = block_sum(s, tmp);
    sq = block_sum(sq, tmp);
    if (threadIdx.x == 0) {
        float m = s / LSEQ;
        float var = sq / LSEQ - m*m;
        if (var < 0.f) var = 0.f;
        mean[bc] = m;
        stdv[bc] = sqrtf(var + EPSV);
    }
}

// ---------------------------------------------------------------- embedding
__global__ __launch_bounds__(256) void embed_kernel(const float* __restrict__ x,
                                                    const float* __restrict__ token_w,
                                                    const float* __restrict__ time_w,
                                                    const float* __restrict__ mean,
                                                    const float* __restrict__ stdv,
                                                    float* __restrict__ h) {
    int bl = blockIdx.x;
    int b = bl >> 9, l = bl & 511;
    __shared__ float sxc[ENC_IN*3];
    if (threadIdx.x < ENC_IN*3) {
        int c = threadIdx.x / 3, k = threadIdx.x % 3;
        int lk = (l + k - 1) & 511;
        float v = x[((size_t)(b*LSEQ + lk))*ENC_IN + c];
        sxc[threadIdx.x] = (v - mean[b*ENC_IN + c]) / stdv[b*ENC_IN + c];
    }
    __syncthreads();
    #pragma unroll
    for (int i = 0; i < 3; i++) {
        int d = threadIdx.x + i*256;
        float acc = 0.f;
        const float* w = token_w + (size_t)d*21;
        #pragma unroll
        for (int t = 0; t < 21; t++) acc += sxc[t] * w[t];
        int d2 = d & ~1;
        float div = __expf((float)d2 * (-9.210340371976184f / (float)D_MODEL));
        float ang = (float)l * div;
        float pe = (d & 1) ? cosf(ang) : sinf(ang);
        float tm = ((float)l / (float)LSEQ) * time_w[d];
        h[(size_t)bl*D_MODEL + d] = acc + pe + tm;
    }
}

// ---------------------------------------------------------------- rmsnorm -> bf16 (vectorized)
__global__ __launch_bounds__(256) void rmsnorm_bf16(const float* __restrict__ h,
                                                    const float* __restrict__ w,
                                                    __hip_bfloat16* __restrict__ xn) {
    size_t base = (size_t)blockIdx.x * D_MODEL;
    __shared__ float tmp[4];
    int tid = threadIdx.x;
    f32x4 v = {0.f,0.f,0.f,0.f};
    if (tid < 192) v = *(const f32x4*)(h + base + tid*4);
    float ss = v[0]*v[0] + v[1]*v[1] + v[2]*v[2] + v[3]*v[3];
    ss = block_sum(ss, tmp);
    float inv = rsqrtf(ss / (float)D_MODEL + EPSV);
    if (tid < 192) {
        f32x4 wv = *(const f32x4*)(w + tid*4);
        __hip_bfloat16 o4[4];
        #pragma unroll
        for (int j = 0; j < 4; j++) o4[j] = __float2bfloat16(v[j]*inv*wv[j]);
        *(uint2*)(xn + base + tid*4) = *(uint2*)o4;
    }
}

// ---------------------------------------------------------------- in_proj MFMA GEMM (BM=128 x BN=256, BK=32, 2-buffer ring, counted vmcnt)
// out: col<D_INNER -> xs_bf bf16 row-major; col>=D_INNER -> silu -> gres bf16 BLOCKED [row/16][d][16]
__global__ __launch_bounds__(256) void gemm_inproj(const __hip_bfloat16* __restrict__ A,
                                                   const __hip_bfloat16* __restrict__ Bw,
                                                   __hip_bfloat16* __restrict__ Cxs,
                                                   __hip_bfloat16* __restrict__ Cg) {
    __shared__ __align__(16) __hip_bfloat16 As[2][128*32];   // 16 KB
    __shared__ __align__(16) __hip_bfloat16 Bs[2][256*32];   // 32 KB
    const int K = D_MODEL;
    const int NK = K/32;                                     // 24
    int tid = threadIdx.x, lane = tid & 63, w = tid >> 6;
    int gx = gridDim.x;                                      // 12
    int nwg = gx * gridDim.y;                                // 384
    int orig = blockIdx.y*gx + blockIdx.x;
    int swz = (orig & 7)*(nwg >> 3) + (orig >> 3);
    int m0 = (swz / gx) * 128, n0 = (swz % gx) * 256;
    int wr = w >> 1, wc = w & 1;
    int kq = lane >> 4, rr = lane & 15;

    f32x4 acc[4][8];
    #pragma unroll
    for (int i = 0; i < 4; i++)
        #pragma unroll
        for (int j = 0; j < 8; j++) acc[i][j] = (f32x4){0.f,0.f,0.f,0.f};

    const char* Ab = (const char*)A;
    const char* Bb = (const char*)Bw;
    char* AsB = (char*)As;
    char* BsB = (char*)Bs;

    int cA0 = tid, cA1 = tid + 256;
    int rA0 = cA0 >> 2, qA0 = (cA0 & 3) ^ ((rA0 >> 1) & 3);
    int rA1 = cA1 >> 2, qA1 = (cA1 & 3) ^ ((rA1 >> 1) & 3);
    int sw = (kq ^ ((rr >> 1) & 3)) * 16;

    auto stage = [&](int buf, int kt) {
        int k0 = kt*32;
        glds16(Ab + ((size_t)(m0+rA0)*K + k0 + qA0*8)*2, AsB + buf*8192 + cA0*16);
        glds16(Ab + ((size_t)(m0+rA1)*K + k0 + qA1*8)*2, AsB + buf*8192 + cA1*16);
        #pragma unroll
        for (int j = 0; j < 4; j++) {
            int idx = j*256 + tid;
            int r = idx >> 2, q = (idx & 3) ^ ((r >> 1) & 3);
            glds16(Bb + ((size_t)(n0+r)*K + k0 + q*8)*2, BsB + buf*16384 + idx*16);
        }
    };

    stage(0, 0);

    for (int k = 0; k < NK; k++) {
        int cur = k & 1;
        if (k + 1 < NK) {
            stage(cur ^ 1, k + 1);
            asm volatile("s_waitcnt vmcnt(6)" ::: "memory");   // cur's 6 loads retired
        } else {
            asm volatile("s_waitcnt vmcnt(0)" ::: "memory");
        }
        __builtin_amdgcn_s_barrier();                 // cur ready for all waves
        bf16x8 af[4], bfr[8];
        #pragma unroll
        for (int mi = 0; mi < 4; mi++) af[mi]  = *(const bf16x8*)(AsB + cur*8192  + (wr*64 + mi*16 + rr)*64 + sw);
        #pragma unroll
        for (int ni = 0; ni < 8; ni++) bfr[ni] = *(const bf16x8*)(BsB + cur*16384 + (wc*128 + ni*16 + rr)*64 + sw);
        __builtin_amdgcn_s_setprio(1);
        #pragma unroll
        for (int mi = 0; mi < 4; mi++)
            #pragma unroll
            for (int ni = 0; ni < 8; ni++)
                acc[mi][ni] = __builtin_amdgcn_mfma_f32_16x16x32_bf16(af[mi], bfr[ni], acc[mi][ni], 0, 0, 0);
        __builtin_amdgcn_s_setprio(0);
        __builtin_amdgcn_s_barrier();                 // all waves done reading cur (next stage overwrites it)
    }

    #pragma unroll
    for (int mi = 0; mi < 4; mi++) {
        #pragma unroll
        for (int ni = 0; ni < 8; ni++) {
            int row0 = m0 + wr*64 + mi*16;
            int col  = n0 + wc*128 + ni*16 + rr;
            if (col >= D_INNER) {
                __hip_bfloat16 g4[4];
                #pragma unroll
                for (int r = 0; r < 4; r++) {
                    float v = acc[mi][ni][r];
                    g4[r] = __float2bfloat16(v / (1.f + __expf(-v)));   // silu
                }
                int cd = col - D_INNER;
                *(uint2*)&Cg[((size_t)(row0 >> 4)*D_INNER + cd)*16 + kq*4] = *(uint2*)g4;
            } else {
                #pragma unroll
                for (int r = 0; r < 4; r++) {
                    int row = row0 + kq*4 + r;
                    Cxs[(size_t)row*D_INNER + col] = __float2bfloat16(acc[mi][ni][r]);
                }
            }
        }
    }
}

// ---------------------------------------------------------------- dtproj MFMA (K=64, fused split-K reduction of pout)
__global__ __launch_bounds__(256) void gemm_dtproj(const float* __restrict__ P,
                                                   const __hip_bfloat16* __restrict__ Bw,
                                                   const float* __restrict__ bias,
                                                   float* __restrict__ xdbl,
                                                   __hip_bfloat16* __restrict__ delta) {
    __shared__ __align__(16) __hip_bfloat16 As[128*64];
    __shared__ __align__(16) __hip_bfloat16 Bs[128*64];
    const int K = 64;
    int tid = threadIdx.x, lane = tid & 63, w = tid >> 6;
    int gx = gridDim.x;
    int nwg = gx * gridDim.y;
    int orig = blockIdx.y*gx + blockIdx.x;
    int swz = (orig & 7)*(nwg >> 3) + (orig >> 3);
    int m0 = (swz / gx) * 128, n0 = (swz % gx) * 128;
    int wr = w >> 1, wc = w & 1;
    int kq = lane >> 4, rr = lane & 15;

    f32x4 acc[4][4];
    #pragma unroll
    for (int i = 0; i < 4; i++)
        #pragma unroll
        for (int j = 0; j < 4; j++) acc[i][j] = (f32x4){0.f,0.f,0.f,0.f};

    const char* Bb = (const char*)Bw;
    char* AsB = (char*)As;
    char* BsB = (char*)Bs;

    #pragma unroll
    for (int c = 0; c < 4; c++) {
        int idx = c*256 + tid;
        int r = idx >> 3, q = idx & 7;
        int qs = q ^ (r & 7);
        glds16(Bb + ((size_t)(n0+r)*K + qs*8)*2, BsB + idx*16);
    }

    const size_t RX = (size_t)ROWS*XN;
    #pragma unroll
    for (int it = 0; it < 2; it++) {
        int idx = it*1024 + tid;
        if (idx < 128*10) {
            int row = idx / 10, ch = idx % 10;
            const float* p0 = P + (size_t)(m0+row)*XN + ch*8;
            f32x4 a0 = *(const f32x4*)(p0)      + *(const f32x4*)(p0+RX)
                     + *(const f32x4*)(p0+2*RX) + *(const f32x4*)(p0+3*RX);
            f32x4 a1 = *(const f32x4*)(p0+4)        + *(const f32x4*)(p0+RX+4)
                     + *(const f32x4*)(p0+2*RX+4)   + *(const f32x4*)(p0+3*RX+4);
            if (n0 == 0) {
                float* xd = xdbl + (size_t)(m0+row)*XN + ch*8;
                *(f32x4*)(xd)   = a0;
                *(f32x4*)(xd+4) = a1;
            }
            if (ch < 8) {
                bf16x8 hv;
                if (ch < 6) {
                    #pragma unroll
                    for (int j = 0; j < 4; j++) { hv[j] = (__bf16)a0[j]; hv[4+j] = (__bf16)a1[j]; }
                } else {
                    bf16x8 z = {}; hv = z;
                }
                *(bf16x8*)(AsB + row*128 + ((ch ^ (row & 7))*16)) = hv;
            }
        }
    }
    __syncthreads();

    #pragma unroll
    for (int kh = 0; kh < 2; kh++) {
        int ch = ((kh*4 + kq) ^ (rr & 7)) * 16;
        bf16x8 af[4], bfr[4];
        #pragma unroll
        for (int mi = 0; mi < 4; mi++) af[mi]  = *(const bf16x8*)(AsB + (wr*64 + mi*16 + rr)*128 + ch);
        #pragma unroll
        for (int ni = 0; ni < 4; ni++) bfr[ni] = *(const bf16x8*)(BsB + (wc*64 + ni*16 + rr)*128 + ch);
        #pragma unroll
        for (int mi = 0; mi < 4; mi++)
            #pragma unroll
            for (int ni = 0; ni < 4; ni++)
                acc[mi][ni] = __builtin_amdgcn_mfma_f32_16x16x32_bf16(af[mi], bfr[ni], acc[mi][ni], 0, 0, 0);
    }

    #pragma unroll
    for (int mi = 0; mi < 4; mi++) {
        #pragma unroll
        for (int ni = 0; ni < 4; ni++) {
            int row0 = m0 + wr*64 + mi*16;
            int col  = n0 + wc*64 + ni*16 + rr;
            __hip_bfloat16 d4[4];
            #pragma unroll
            for (int r = 0; r < 4; r++) {
                float v = acc[mi][ni][r] + bias[col];
                d4[r] = __float2bfloat16(softplusf(v));
            }
            *(uint2*)&delta[((size_t)(row0 >> 4)*D_INNER + col)*16 + kq*4] = *(uint2*)d4;
        }
    }
}

// ---------------------------------------------------------------- out_proj: h += ygate @ W^T (BM=128 BN=64, 3-ring, tail-correct)
__global__ __launch_bounds__(256) void gemm_outproj(const __hip_bfloat16* __restrict__ A,
                                                    const __hip_bfloat16* __restrict__ Bw,
                                                    float* __restrict__ C) {
    __shared__ __align__(16) __hip_bfloat16 As[3][128*32];   // 24 KB
    __shared__ __align__(16) __hip_bfloat16 Bs[3][64*32];    // 12 KB
    int tid = threadIdx.x, lane = tid & 63, w = tid >> 6;
    int gx = gridDim.x;                       // 12
    int nwg = gx * gridDim.y;                 // 384
    int orig = blockIdx.y*gx + blockIdx.x;
    int swz = (orig & 7)*(nwg >> 3) + (orig >> 3);
    int m0 = (swz / gx) * 128, n0 = (swz % gx) * 64;
    int wr = w >> 1, wc = w & 1;
    int kq = lane >> 4, rr = lane & 15;
    const int K = D_INNER;
    const int NK = K/32;                      // 48

    f32x4 acc[4][2];
    #pragma unroll
    for (int i = 0; i < 4; i++)
        #pragma unroll
        for (int j = 0; j < 2; j++) acc[i][j] = (f32x4){0.f,0.f,0.f,0.f};

    const char* Ab = (const char*)A;
    const char* Bb = (const char*)Bw;
    char* AsB = (char*)As;
    char* BsB = (char*)Bs;

    int cA0 = tid, cA1 = tid + 256;
    int rA0 = cA0 >> 2, qA0 = (cA0 & 3) ^ ((rA0 >> 1) & 3);
    int rA1 = cA1 >> 2, qA1 = (cA1 & 3) ^ ((rA1 >> 1) & 3);
    int rB = tid >> 2,  qB  = (tid & 3) ^ ((rB >> 1) & 3);
    int sw = (kq ^ ((rr >> 1) & 3)) * 16;

    auto stage = [&](int buf, int kt) {
        int k0 = kt*32;
        glds16(Ab + ((size_t)(m0+rA0)*K + k0 + qA0*8)*2, AsB + buf*8192 + cA0*16);
        glds16(Ab + ((size_t)(m0+rA1)*K + k0 + qA1*8)*2, AsB + buf*8192 + cA1*16);
        glds16(Bb + ((size_t)(n0+rB)*K + k0 + qB*8)*2,  BsB + buf*4096 + tid*16);
    };

    stage(0, 0);
    stage(1, 1);

    for (int k = 0; k < NK; k++) {
        int cur = k % 3;
        __builtin_amdgcn_s_barrier();
        if (k + 2 < NK) stage((k + 2) % 3, k + 2);
        if (k + 2 < NK)      asm volatile("s_waitcnt vmcnt(6)" ::: "memory");
        else if (k + 1 < NK) asm volatile("s_waitcnt vmcnt(3)" ::: "memory");
        else                 asm volatile("s_waitcnt vmcnt(0)" ::: "memory");
        __builtin_amdgcn_s_barrier();
        bf16x8 af[4], bfr[2];
        #pragma unroll
        for (int mi = 0; mi < 4; mi++) af[mi]  = *(const bf16x8*)(AsB + cur*8192 + (wr*64 + mi*16 + rr)*64 + sw);
        #pragma unroll
        for (int ni = 0; ni < 2; ni++) bfr[ni] = *(const bf16x8*)(BsB + cur*4096 + (wc*32 + ni*16 + rr)*64 + sw);
        __builtin_amdgcn_s_setprio(1);
        #pragma unroll
        for (int mi = 0; mi < 4; mi++)
            #pragma unroll
            for (int ni = 0; ni < 2; ni++)
                acc[mi][ni] = __builtin_amdgcn_mfma_f32_16x16x32_bf16(af[mi], bfr[ni], acc[mi][ni], 0, 0, 0);
        __builtin_amdgcn_s_setprio(0);
    }

    #pragma unroll
    for (int mi = 0; mi < 4; mi++) {
        #pragma unroll
        for (int ni = 0; ni < 2; ni++) {
            #pragma unroll
            for (int r = 0; r < 4; r++) {
                int row = m0 + wr*64 + mi*16 + kq*4 + r;
                int col = n0 + wc*32 + ni*16 + rr;
                size_t o = (size_t)row*D_MODEL + col;
                C[o] = acc[mi][ni][r] + C[o];   // h holds the residual
            }
        }
    }
}

// ---------------------------------------------------------------- xproj MFMA: partials, split-K (3-buffer ring)
__global__ __launch_bounds__(256) void gemm_xproj(const __hip_bfloat16* __restrict__ A,
                                                  const __hip_bfloat16* __restrict__ W,
                                                  float* __restrict__ P) {
    __shared__ __align__(16) __hip_bfloat16 As[3][64*64];
    __shared__ __align__(16) __hip_bfloat16 Bs[3][96*64];
    int tid = threadIdx.x, lane = tid & 63, w = tid >> 6;
    int m0 = blockIdx.x * 64;
    int k0 = blockIdx.y * (D_INNER / KSPLIT);
    int kq = lane >> 4, rr = lane & 15;
    const int NK = (D_INNER/KSPLIT)/64;       // 6
    f32x4 acc[5];
    #pragma unroll
    for (int i = 0; i < 5; i++) acc[i] = (f32x4){0.f,0.f,0.f,0.f};
    const char* Ab = (const char*)A;
    const char* Wb = (const char*)W;
    char* AsB = (char*)As;
    char* BsB = (char*)Bs;

    auto stage = [&](int buf, int it) {
        int kk = k0 + it*64;
        #pragma unroll
        for (int cA = 0; cA < 2; cA++) {
            int idx = cA*256 + tid;
            int r = idx >> 3, q = (idx & 7) ^ (r & 7);
            glds16(Ab + ((size_t)(m0+r)*D_INNER + kk + q*8)*2, AsB + buf*8192 + idx*16);
        }
        #pragma unroll
        for (int cB = 0; cB < 3; cB++) {
            int idx = cB*256 + tid;
            int r = idx >> 3, q = (idx & 7) ^ (r & 7);
            int rs = r < XN ? r : XN-1;
            glds16(Wb + ((size_t)rs*D_INNER + kk + q*8)*2, BsB + buf*12288 + idx*16);
        }
    };

    stage(0, 0);
    stage(1, 1);

    for (int it = 0; it < NK; it++) {
        int cur = it % 3;
        __builtin_amdgcn_s_barrier();
        if (it + 2 < NK) stage((it + 2) % 3, it + 2);
        if (it + 2 < NK)      asm volatile("s_waitcnt vmcnt(10)" ::: "memory");
        else if (it + 1 < NK) asm volatile("s_waitcnt vmcnt(5)" ::: "memory");
        else                  asm volatile("s_waitcnt vmcnt(0)" ::: "memory");
        __builtin_amdgcn_s_barrier();
        #pragma unroll
        for (int kh = 0; kh < 2; kh++) {
            bf16x8 a = *(const bf16x8*)(AsB + cur*8192 + (w*16 + rr)*128 + (((kh*4 + kq) ^ (rr & 7)))*16);
            #pragma unroll
            for (int ni = 0; ni < 5; ni++) {
                bf16x8 b = *(const bf16x8*)(BsB + cur*12288 + (ni*16 + rr)*128 + (((kh*4 + kq) ^ (rr & 7)))*16);
                acc[ni] = __builtin_amdgcn_mfma_f32_16x16x32_bf16(a, b, acc[ni], 0, 0, 0);
            }
        }
    }
    float* Cp = P + (size_t)blockIdx.y * ROWS * XN;
    #pragma unroll
    for (int ni = 0; ni < 5; ni++)
        #pragma unroll
        for (int r = 0; r < 4; r++) {
            int row = m0 + w*16 + kq*4 + r;
            int col = ni*16 + rr;
            Cp[(size_t)row*XN + col] = acc[ni][r];
        }
}

// ---------------------------------------------------------------- depthwise causal conv + SiLU (bf16 in/out, x8 vec)
__global__ __launch_bounds__(256) void dwconv_silu(const __hip_bfloat16* __restrict__ xs,
                                                   const float* __restrict__ cw,
                                                   const float* __restrict__ cb,
                                                   __hip_bfloat16* __restrict__ u_bf) {
    int idx = blockIdx.x*256 + threadIdx.x;
    int dg = idx % (D_INNER/8);
    int t  = idx / (D_INNER/8);
    if (t >= ROWS) return;
    int d0 = dg*8;
    int l = t & 511, b = t >> 9;
    bf16x8 rows[K_CONV];
    #pragma unroll
    for (int k = 0; k < K_CONV; k++) {
        int ll = l - (K_CONV-1) + k;
        if (ll >= 0) rows[k] = *(const bf16x8*)(xs + ((size_t)(b*LSEQ + ll))*D_INNER + d0);
        else { bf16x8 z = {}; rows[k] = z; }
    }
    bf16x8 outv;
    #pragma unroll
    for (int j = 0; j < 8; j++) {
        int d = d0 + j;
        const float4 w4 = *(const float4*)(cw + d*K_CONV);
        float acc = cb[d]
                  + (float)rows[0][j]*w4.x + (float)rows[1][j]*w4.y
                  + (float)rows[2][j]*w4.z + (float)rows[3][j]*w4.w;
        float v = acc / (1.f + __expf(-acc));
        outv[j] = (__bf16)v;
    }
    *(bf16x8*)(u_bf + (size_t)t*D_INNER + d0) = outv;
}

// ---------------------------------------------------------------- selective scan, 3-phase chunked (NC=16, CL=32)
__global__ __launch_bounds__(256) void scan_p1(const __hip_bfloat16* __restrict__ u,
                                               const __hip_bfloat16* __restrict__ delta_blk,
                                               const float* __restrict__ xdbl,
                                               const float* __restrict__ A_log,
                                               float* __restrict__ xfin,
                                               float* __restrict__ sumdlt) {
    int d = blockIdx.x*256 + threadIdx.x;
    int c = blockIdx.y, b = blockIdx.z;
    int l0 = c*CL;
    const float* al = A_log + d*N_STATE;
    bool fast = true;
    #pragma unroll
    for (int n = 0; n < N_STATE; n++)
        fast = fast && (fabsf(__expf(al[n]) - (float)(n+1)) < 1e-3f);
    float xs[N_STATE];
    #pragma unroll
    for (int n = 0; n < N_STATE; n++) xs[n] = 0.f;
    const __hip_bfloat16* pu = u + (size_t)(b*LSEQ + l0)*D_INNER + d;
    const float* pB = xdbl + (size_t)(b*LSEQ + l0)*XN + DT_RANK;
    float sd = 0.f;
    if (fast) {
        #pragma unroll
        for (int tt = 0; tt < 2; tt++) {
            const __hip_bfloat16* db = delta_blk + ((size_t)(b*NTILE + (l0>>4) + tt)*D_INNER + d)*16;
            bf16x8 d0 = *(const bf16x8*)db;
            bf16x8 d1 = *(const bf16x8*)(db + 8);
            #pragma unroll
            for (int i = 0; i < 16; i++) {
                float dlt = (float)(i < 8 ? d0[i] : d1[i-8]);
                float uu = __bfloat162float(*pu); pu += D_INNER;
                float du = dlt*uu;
                sd += dlt;
                float e1 = fexp2(-dlt*LOG2E);
                float e = e1;
                xs[0] = e*xs[0] + du*pB[0];
                #pragma unroll
                for (int n = 1; n < N_STATE; n++) {
                    e *= e1;
                    xs[n] = e*xs[n] + du*pB[n];
                }
                pB += XN;
            }
        }
    } else {
        #pragma unroll
        for (int tt = 0; tt < 2; tt++) {
            const __hip_bfloat16* db = delta_blk + ((size_t)(b*NTILE + (l0>>4) + tt)*D_INNER + d)*16;
            bf16x8 d0 = *(const bf16x8*)db;
            bf16x8 d1 = *(const bf16x8*)(db + 8);
            #pragma unroll
            for (int i = 0; i < 16; i++) {
                float dlt = (float)(i < 8 ? d0[i] : d1[i-8]);
                float uu = __bfloat162float(*pu); pu += D_INNER;
                float du = dlt*uu;
                sd += dlt;
                #pragma unroll
                for (int n = 0; n < N_STATE; n++) {
                    float A2n = -__expf(al[n]) * LOG2E;
                    xs[n] = fexp2(dlt*A2n)*xs[n] + du*pB[n];
                }
                pB += XN;
            }
        }
    }
    float* px = xfin + (size_t)((b*NC + c)*N_STATE)*D_INNER + d;
    #pragma unroll
    for (int n = 0; n < N_STATE; n++) px[n*D_INNER] = xs[n];
    sumdlt[(size_t)(b*NC + c)*D_INNER + d] = sd;
}

__global__ __launch_bounds__(256) void scan_p2(float* __restrict__ xfin,
                                               const float* __restrict__ sumdlt,
                                               const float* __restrict__ A_log) {
    int idx = blockIdx.x*256 + threadIdx.x;
    int d = idx % D_INNER;
    int r = idx / D_INNER;
    int n = r & 15;
    int b = r >> 4;
    float A2 = -__expf(A_log[d*N_STATE + n]) * LOG2E;
    float cr = 0.f;
    for (int c = 1; c < NC; c++) {
        size_t jp = (size_t)(b*NC + c - 1);
        float xf = xfin[(jp*N_STATE + n)*D_INNER + d];
        float s  = sumdlt[jp*D_INNER + d];
        cr = fexp2(A2 * s) * cr + xf;
        xfin[(jp*N_STATE + n)*D_INNER + d] = cr;
    }
}

__global__ __launch_bounds__(256) void scan_p3(const __hip_bfloat16* __restrict__ u,
                                               const __hip_bfloat16* __restrict__ delta_blk,
                                               const __hip_bfloat16* __restrict__ gres,
                                               const float* __restrict__ xdbl,
                                               const float* __restrict__ A_log,
                                               const float* __restrict__ Dp,
                                               const float* __restrict__ carry,
                                               __hip_bfloat16* __restrict__ ygate) {
    int d = blockIdx.x*256 + threadIdx.x;
    int c = blockIdx.y, b = blockIdx.z;
    int l0 = c*CL;
    const float* al = A_log + d*N_STATE;
    bool fast = true;
    #pragma unroll
    for (int n = 0; n < N_STATE; n++)
        fast = fast && (fabsf(__expf(al[n]) - (float)(n+1)) < 1e-3f);
    float xs[N_STATE];
    if (c == 0) {
        #pragma unroll
        for (int n = 0; n < N_STATE; n++) xs[n] = 0.f;
    } else {
        const float* pc = carry + (size_t)((b*NC + c - 1)*N_STATE)*D_INNER + d;
        #pragma unroll
        for (int n = 0; n < N_STATE; n++) xs[n] = pc[n*D_INNER];
    }
    float Dv = Dp[d];
    const __hip_bfloat16* pu = u + (size_t)(b*LSEQ + l0)*D_INNER + d;
    const float* pB = xdbl + (size_t)(b*LSEQ + l0)*XN + DT_RANK;
    __hip_bfloat16* py = ygate + (size_t)(b*LSEQ + l0)*D_INNER + d;
    if (fast) {
        #pragma unroll
        for (int tt = 0; tt < 2; tt++) {
            size_t tb = (size_t)(b*NTILE + (l0>>4) + tt)*D_INNER + d;
            const __hip_bfloat16* db = delta_blk + tb*16;
            bf16x8 d0 = *(const bf16x8*)db;
            bf16x8 d1 = *(const bf16x8*)(db + 8);
            const __hip_bfloat16* gb = gres + tb*16;
            bf16x8 g0 = *(const bf16x8*)gb;
            bf16x8 g1 = *(const bf16x8*)(gb + 8);
            #pragma unroll
            for (int i = 0; i < 16; i++) {
                float dlt = (float)(i < 8 ? d0[i] : d1[i-8]);
                float gr  = (float)(i < 8 ? g0[i] : g1[i-8]);
                float uu = __bfloat162float(*pu); pu += D_INNER;
                float du = dlt*uu;
                float e1 = fexp2(-dlt*LOG2E);
                float e = e1;
                float acc;
                xs[0] = e*xs[0] + du*pB[0];
                acc = xs[0]*pB[N_STATE + 0];
                #pragma unroll
                for (int n = 1; n < N_STATE; n++) {
                    e *= e1;
                    xs[n] = e*xs[n] + du*pB[n];
                    acc += xs[n]*pB[N_STATE + n];
                }
                pB += XN;
                float y = acc + uu*Dv;
                *py = __float2bfloat16(y * gr); py += D_INNER;
            }
        }
    } else {
        #pragma unroll
        for (int tt = 0; tt < 2; tt++) {
            size_t tb = (size_t)(b*NTILE + (l0>>4) + tt)*D_INNER + d;
            const __hip_bfloat16* db = delta_blk + tb*16;
            bf16x8 d0 = *(const bf16x8*)db;
            bf16x8 d1 = *(const bf16x8*)(db + 8);
            const __hip_bfloat16* gb = gres + tb*16;
            bf16x8 g0 = *(const bf16x8*)gb;
            bf16x8 g1 = *(const bf16x8*)(gb + 8);
            #pragma unroll
            for (int i = 0; i < 16; i++) {
                float dlt = (float)(i < 8 ? d0[i] : d1[i-8]);
                float gr  = (float)(i < 8 ? g0[i] : g1[i-8]);
                float uu = __bfloat162float(*pu); pu += D_INNER;
                float du = dlt*uu;
                float acc = 0.f;
                #pragma unroll
                for (int n = 0; n < N_STATE; n++) {
                    float A2n = -__expf(al[n]) * LOG2E;
                    xs[n] = fexp2(dlt*A2n)*xs[n] + du*pB[n];
                    acc += xs[n]*pB[N_STATE + n];
                }
                pB += XN;
                float y = acc + uu*Dv;
                *py = __float2bfloat16(y * gr); py += D_INNER;
            }
        }
    }
}

// ---------------------------------------------------------------- final norm + head + de-norm
__global__ __launch_bounds__(256) void final_kernel(const float* __restrict__ h,
                                                    const float* __restrict__ fnw,
                                                    const float* __restrict__ out_w,
                                                    const float* __restrict__ mean,
                                                    const float* __restrict__ stdv,
                                                    float* __restrict__ out) {
    int bid = blockIdx.x;
    int b = bid / PRED_LEN, lo = bid % PRED_LEN;
    int l = LSEQ - PRED_LEN + lo;
    const float* row = h + ((size_t)(b*LSEQ + l))*D_MODEL;
    __shared__ float tmp[4];
    float ss = 0.f;
    for (int k = threadIdx.x; k < D_MODEL; k += 256) { float v = row[k]; ss += v*v; }
    ss = block_sum(ss, tmp);
    float inv = rsqrtf(ss / (float)D_MODEL + EPSV);
    float acc[C_OUT] = {};
    for (int k = threadIdx.x; k < D_MODEL; k += 256) {
        float hn = row[k]*fnw[k];
        #pragma unroll
        for (int c = 0; c < C_OUT; c++) acc[c] += hn*out_w[c*D_MODEL + k];
    }
    #pragma unroll
    for (int c = 0; c < C_OUT; c++) {
        float s = block_sum(acc[c], tmp);
        if (threadIdx.x == 0)
            out[((size_t)(b*PRED_LEN + lo))*C_OUT + c] = s*inv*stdv[b*ENC_IN + c] + mean[b*ENC_IN + c];
    }
}

// ---------------------------------------------------------------- launch
extern "C" void kernel_launch(void* const* d_in, const int* in_sizes, int n_in,
                              void* d_out, int out_size, void* d_ws, size_t ws_size,
                              hipStream_t stream) {
    const float* x        = (const float*)d_in[0];
    const float* token_w  = (const float*)d_in[1];
    const float* time_w   = (const float*)d_in[2];
    const float* norm_w   = (const float*)d_in[3];
    const float* in_w     = (const float*)d_in[4];
    const float* conv_w   = (const float*)d_in[5];
    const float* conv_b   = (const float*)d_in[6];
    const float* xproj_w  = (const float*)d_in[7];
    const float* dtproj_w = (const float*)d_in[8];
    const float* dtproj_b = (const float*)d_in[9];
    const float* A_log    = (const float*)d_in[10];
    const float* Dp       = (const float*)d_in[11];
    const float* outproj_w= (const float*)d_in[12];
    const float* final_nw = (const float*)d_in[13];
    const float* out_w    = (const float*)d_in[14];
    float* out = (float*)d_out;

    float* ws   = (float*)d_ws;
    float* mean = ws;
    float* stdv = ws + 64;
    float* h    = ws + 128;                            // ROWS*D_MODEL
    float* xdbl = h    + (size_t)ROWS*D_MODEL;         // ROWS*80 f32
    float* sumd = xdbl + (size_t)ROWS*XN;              // BSZ*NC*D_INNER
    float* xfin = sumd + (size_t)BSZ*NC*D_INNER;       // BSZ*NC*N_STATE*D_INNER
    float* pout = xfin + (size_t)BSZ*NC*D_INNER*N_STATE; // KSPLIT*ROWS*XN partials
    float* fend = pout + (size_t)KSPLIT*ROWS*XN;
    __hip_bfloat16* xn_bf  = (__hip_bfloat16*)fend;
    __hip_bfloat16* xs_bf  = xn_bf + (size_t)ROWS*D_MODEL;
    __hip_bfloat16* u_bf   = xs_bf + (size_t)ROWS*D_INNER;
    __hip_bfloat16* gres   = u_bf  + (size_t)ROWS*D_INNER;
    __hip_bfloat16* ygate  = gres  + (size_t)ROWS*D_INNER;
    __hip_bfloat16* delta  = ygate + (size_t)ROWS*D_INNER;
    __hip_bfloat16* inw_bf = delta + (size_t)ROWS*D_INNER;
    __hip_bfloat16* outw_bf= inw_bf + (size_t)E_LAYERS*2*D_INNER*D_MODEL;
    __hip_bfloat16* xpw_bf = outw_bf+ (size_t)E_LAYERS*D_MODEL*D_INNER;
    __hip_bfloat16* dtw_bf = xpw_bf + (size_t)E_LAYERS*XN*D_INNER;

    {
        const int NT = E_LAYERS*2*D_INNER*D_MODEL + E_LAYERS*D_MODEL*D_INNER
                     + E_LAYERS*XN*D_INNER + E_LAYERS*D_INNER*64;
        cvt_all<<<(NT+255)/256, 256, 0, stream>>>(in_w, outproj_w, xproj_w, dtproj_w,
                                                  inw_bf, outw_bf, xpw_bf, dtw_bf);
    }

    stats_kernel<<<BSZ*ENC_IN, 256, 0, stream>>>(x, mean, stdv);
    embed_kernel<<<ROWS, 256, 0, stream>>>(x, token_w, time_w, mean, stdv, h);

    for (int e = 0; e < E_LAYERS; e++) {
        rmsnorm_bf16<<<ROWS, 256, 0, stream>>>(h, norm_w + e*D_MODEL, xn_bf);
        gemm_inproj<<<dim3(2*D_INNER/256, ROWS/128), 256, 0, stream>>>(
            xn_bf, inw_bf + (size_t)e*2*D_INNER*D_MODEL, xs_bf, gres);
        dwconv_silu<<<(ROWS*(D_INNER/8) + 255)/256, 256, 0, stream>>>(
            xs_bf, conv_w + (size_t)e*D_INNER*K_CONV, conv_b + e*D_INNER, u_bf);
        gemm_xproj<<<dim3(ROWS/64, KSPLIT), 256, 0, stream>>>(
            u_bf, xpw_bf + (size_t)e*XN*D_INNER, pout);
        gemm_dtproj<<<dim3(D_INNER/128, ROWS/128), 256, 0, stream>>>(
            pout, dtw_bf + (size_t)e*D_INNER*64, dtproj_b + e*D_INNER, xdbl, delta);
        const float* Alog_e = A_log + (size_t)e*D_INNER*N_STATE;
        scan_p1<<<dim3(D_INNER/256, NC, BSZ), 256, 0, stream>>>(
            u_bf, delta, xdbl, Alog_e, xfin, sumd);
        scan_p2<<<(BSZ*D_INNER*N_STATE)/256, 256, 0, stream>>>(
            xfin, sumd, Alog_e);
        scan_p3<<<dim3(D_INNER/256, NC, BSZ), 256, 0, stream>>>(
            u_bf, delta, gres, xdbl, Alog_e, Dp + (size_t)e*D_INNER, xfin, ygate);
        gemm_outproj<<<dim3(D_MODEL/64, ROWS/128), 256, 0, stream>>>(
            ygate, outw_bf + (size_t)e*D_MODEL*D_INNER, h);
    }

    final_kernel<<<BSZ*PRED_LEN, 256, 0, stream>>>(h, final_nw, out_w, mean, stdv, out);
}

// Round 14
// 380.686 us; speedup vs baseline: 1.0554x; 1.0554x over previous
//
#include <hip/hip_runtime.h>
#include <hip/hip_bf16.h>
#include <math.h>

// Problem constants
#define BSZ 8
#define LSEQ 512
#define ENC_IN 7
#define D_MODEL 768
#define D_INNER 1536
#define DT_RANK 48
#define N_STATE 16
#define K_CONV 4
#define E_LAYERS 2
#define C_OUT 7
#define PRED_LEN 96
#define EPSV 1e-5f
#define XN 80
#define KSPLIT 4

#define ROWS (BSZ*LSEQ)            // 4096
#define NC 16                      // scan chunks
#define CL (LSEQ/NC)               // 32 steps per chunk
#define NTILE (LSEQ/16)            // 32 16-step tiles per batch
#define LOG2E 1.44269504088896f

typedef __bf16 bf16x8 __attribute__((ext_vector_type(8)));
typedef float  f32x4  __attribute__((ext_vector_type(4)));

// raw hardware exp2 (single v_exp_f32)
__device__ __forceinline__ float fexp2(float x) {
    float r;
    asm("v_exp_f32 %0, %1" : "=v"(r) : "v"(x));
    return r;
}
__device__ __forceinline__ float softplusf(float v) {
    return fmaxf(v, 0.f) + log1pf(__expf(-fabsf(v)));
}
__device__ __forceinline__ void glds16(const char* g, char* l) {
    __builtin_amdgcn_global_load_lds((const __attribute__((address_space(1))) unsigned int*)g,
                                     (__attribute__((address_space(3))) unsigned int*)l, 16, 0, 0);
}

// ---------------------------------------------------------------- utilities
__device__ __forceinline__ float block_sum(float v, float* tmp) {
    #pragma unroll
    for (int off = 32; off > 0; off >>= 1) v += __shfl_down(v, off);
    int lane = threadIdx.x & 63, wid = threadIdx.x >> 6;
    __syncthreads();
    if (lane == 0) tmp[wid] = v;
    __syncthreads();
    return tmp[0] + tmp[1] + tmp[2] + tmp[3];
}

// ---------------------------------------------------------------- fused weight conversion (one launch)
__global__ __launch_bounds__(256) void cvt_all(const float* __restrict__ in_w,
                                               const float* __restrict__ outw,
                                               const float* __restrict__ xpw,
                                               const float* __restrict__ dtw,
                                               __hip_bfloat16* __restrict__ inw_bf,
                                               __hip_bfloat16* __restrict__ outw_bf,
                                               __hip_bfloat16* __restrict__ xpw_bf,
                                               __hip_bfloat16* __restrict__ dtw_bf) {
    const int N1 = E_LAYERS*2*D_INNER*D_MODEL;
    const int N2 = E_LAYERS*D_MODEL*D_INNER;
    const int N3 = E_LAYERS*XN*D_INNER;
    const int N4 = E_LAYERS*D_INNER*64;
    int i = blockIdx.x*256 + threadIdx.x;
    if (i < N1) {
        inw_bf[i] = __float2bfloat16(in_w[i]);
    } else if (i < N1+N2) {
        int j = i - N1; outw_bf[j] = __float2bfloat16(outw[j]);
    } else if (i < N1+N2+N3) {
        int j = i - N1 - N2; xpw_bf[j] = __float2bfloat16(xpw[j]);
    } else if (i < N1+N2+N3+N4) {
        int j = i - N1 - N2 - N3;
        int r = j >> 6, c = j & 63;
        dtw_bf[j] = __float2bfloat16(c < DT_RANK ? dtw[r*DT_RANK + c] : 0.f);
    }
}

// ---------------------------------------------------------------- stats (RevIN)
__global__ __launch_bounds__(256) void stats_kernel(const float* __restrict__ x,
                                                    float* __restrict__ mean,
                                                    float* __restrict__ stdv) {
    int bc = blockIdx.x;
    int b = bc / ENC_IN, c = bc % ENC_IN;
    __shared__ float tmp[4];
    float s = 0.f, sq = 0.f;
    for (int l = threadIdx.x; l < LSEQ; l += 256) {
        float v = x[((size_t)(b*LSEQ + l))*ENC_IN + c];
        s += v; sq += v*v;
    }
    s = block_sum(s, tmp);
    sq = block_sum(sq, tmp);
    if (threadIdx.x == 0) {
        float m = s / LSEQ;
        float var = sq / LSEQ - m*m;
        if (var < 0.f) var = 0.f;
        mean[bc] = m;
        stdv[bc] = sqrtf(var + EPSV);
    }
}

// ---------------------------------------------------------------- embedding
__global__ __launch_bounds__(256) void embed_kernel(const float* __restrict__ x,
                                                    const float* __restrict__ token_w,
                                                    const float* __restrict__ time_w,
                                                    const float* __restrict__ mean,
                                                    const float* __restrict__ stdv,
                                                    float* __restrict__ h) {
    int bl = blockIdx.x;
    int b = bl >> 9, l = bl & 511;
    __shared__ float sxc[ENC_IN*3];
    if (threadIdx.x < ENC_IN*3) {
        int c = threadIdx.x / 3, k = threadIdx.x % 3;
        int lk = (l + k - 1) & 511;
        float v = x[((size_t)(b*LSEQ + lk))*ENC_IN + c];
        sxc[threadIdx.x] = (v - mean[b*ENC_IN + c]) / stdv[b*ENC_IN + c];
    }
    __syncthreads();
    #pragma unroll
    for (int i = 0; i < 3; i++) {
        int d = threadIdx.x + i*256;
        float acc = 0.f;
        const float* w = token_w + (size_t)d*21;
        #pragma unroll
        for (int t = 0; t < 21; t++) acc += sxc[t] * w[t];
        int d2 = d & ~1;
        float div = __expf((float)d2 * (-9.210340371976184f / (float)D_MODEL));
        float ang = (float)l * div;
        float pe = (d & 1) ? cosf(ang) : sinf(ang);
        float tm = ((float)l / (float)LSEQ) * time_w[d];
        h[(size_t)bl*D_MODEL + d] = acc + pe + tm;
    }
}

// ---------------------------------------------------------------- rmsnorm -> bf16 (vectorized)
__global__ __launch_bounds__(256) void rmsnorm_bf16(const float* __restrict__ h,
                                                    const float* __restrict__ w,
                                                    __hip_bfloat16* __restrict__ xn) {
    size_t base = (size_t)blockIdx.x * D_MODEL;
    __shared__ float tmp[4];
    int tid = threadIdx.x;
    f32x4 v = {0.f,0.f,0.f,0.f};
    if (tid < 192) v = *(const f32x4*)(h + base + tid*4);
    float ss = v[0]*v[0] + v[1]*v[1] + v[2]*v[2] + v[3]*v[3];
    ss = block_sum(ss, tmp);
    float inv = rsqrtf(ss / (float)D_MODEL + EPSV);
    if (tid < 192) {
        f32x4 wv = *(const f32x4*)(w + tid*4);
        __hip_bfloat16 o4[4];
        #pragma unroll
        for (int j = 0; j < 4; j++) o4[j] = __float2bfloat16(v[j]*inv*wv[j]);
        *(uint2*)(xn + base + tid*4) = *(uint2*)o4;
    }
}

// ---------------------------------------------------------------- in_proj MFMA GEMM (BM=128 x BN=128, BK=32, 3-buffer ring, tail-correct)
// out: col<D_INNER -> xs_bf bf16 row-major; col>=D_INNER -> silu -> gres bf16 BLOCKED [row/16][d][16]
__global__ __launch_bounds__(256) void gemm_inproj(const __hip_bfloat16* __restrict__ A,
                                                   const __hip_bfloat16* __restrict__ Bw,
                                                   __hip_bfloat16* __restrict__ Cxs,
                                                   __hip_bfloat16* __restrict__ Cg) {
    __shared__ __align__(16) __hip_bfloat16 As[3][128*32];   // 24 KB
    __shared__ __align__(16) __hip_bfloat16 Bs[3][128*32];   // 24 KB
    const int K = D_MODEL;
    const int NK = K/32;                                     // 24
    int tid = threadIdx.x, lane = tid & 63, w = tid >> 6;
    int gx = gridDim.x;                                      // 24
    int nwg = gx * gridDim.y;                                // 768
    int orig = blockIdx.y*gx + blockIdx.x;
    int swz = (orig & 7)*(nwg >> 3) + (orig >> 3);
    int m0 = (swz / gx) * 128, n0 = (swz % gx) * 128;
    int wr = w >> 1, wc = w & 1;
    int kq = lane >> 4, rr = lane & 15;

    f32x4 acc[4][4];
    #pragma unroll
    for (int i = 0; i < 4; i++)
        #pragma unroll
        for (int j = 0; j < 4; j++) acc[i][j] = (f32x4){0.f,0.f,0.f,0.f};

    const char* Ab = (const char*)A;
    const char* Bb = (const char*)Bw;
    char* AsB = (char*)As;
    char* BsB = (char*)Bs;

    int c0 = tid, c1 = tid + 256;
    int r0 = c0 >> 2, q0 = (c0 & 3) ^ ((r0 >> 1) & 3);
    int r1 = c1 >> 2, q1 = (c1 & 3) ^ ((r1 >> 1) & 3);
    int sw = (kq ^ ((rr >> 1) & 3)) * 16;

    auto stage = [&](int buf, int kt) {
        int k0 = kt*32;
        glds16(Ab + ((size_t)(m0+r0)*K + k0 + q0*8)*2, AsB + buf*8192 + c0*16);
        glds16(Ab + ((size_t)(m0+r1)*K + k0 + q1*8)*2, AsB + buf*8192 + c1*16);
        glds16(Bb + ((size_t)(n0+r0)*K + k0 + q0*8)*2, BsB + buf*8192 + c0*16);
        glds16(Bb + ((size_t)(n0+r1)*K + k0 + q1*8)*2, BsB + buf*8192 + c1*16);
    };

    stage(0, 0);
    stage(1, 1);

    for (int k = 0; k < NK; k++) {
        int cur = k % 3;
        __builtin_amdgcn_s_barrier();                 // all waves done reading buf being overwritten
        if (k + 2 < NK) stage((k + 2) % 3, k + 2);
        if (k + 2 < NK)      asm volatile("s_waitcnt vmcnt(8)" ::: "memory");
        else if (k + 1 < NK) asm volatile("s_waitcnt vmcnt(4)" ::: "memory");
        else                 asm volatile("s_waitcnt vmcnt(0)" ::: "memory");
        __builtin_amdgcn_s_barrier();                 // cur ready for all waves
        bf16x8 af[4], bfr[4];
        #pragma unroll
        for (int mi = 0; mi < 4; mi++) af[mi]  = *(const bf16x8*)(AsB + cur*8192 + (wr*64 + mi*16 + rr)*64 + sw);
        #pragma unroll
        for (int ni = 0; ni < 4; ni++) bfr[ni] = *(const bf16x8*)(BsB + cur*8192 + (wc*64 + ni*16 + rr)*64 + sw);
        __builtin_amdgcn_s_setprio(1);
        #pragma unroll
        for (int mi = 0; mi < 4; mi++)
            #pragma unroll
            for (int ni = 0; ni < 4; ni++)
                acc[mi][ni] = __builtin_amdgcn_mfma_f32_16x16x32_bf16(af[mi], bfr[ni], acc[mi][ni], 0, 0, 0);
        __builtin_amdgcn_s_setprio(0);
    }

    #pragma unroll
    for (int mi = 0; mi < 4; mi++) {
        #pragma unroll
        for (int ni = 0; ni < 4; ni++) {
            int row0 = m0 + wr*64 + mi*16;
            int col  = n0 + wc*64 + ni*16 + rr;
            if (col >= D_INNER) {
                __hip_bfloat16 g4[4];
                #pragma unroll
                for (int r = 0; r < 4; r++) {
                    float v = acc[mi][ni][r];
                    g4[r] = __float2bfloat16(v / (1.f + __expf(-v)));   // silu
                }
                int cd = col - D_INNER;
                *(uint2*)&Cg[((size_t)(row0 >> 4)*D_INNER + cd)*16 + kq*4] = *(uint2*)g4;
            } else {
                #pragma unroll
                for (int r = 0; r < 4; r++) {
                    int row = row0 + kq*4 + r;
                    Cxs[(size_t)row*D_INNER + col] = __float2bfloat16(acc[mi][ni][r]);
                }
            }
        }
    }
}

// ---------------------------------------------------------------- dtproj MFMA (K=64, fused split-K reduction of pout)
__global__ __launch_bounds__(256) void gemm_dtproj(const float* __restrict__ P,
                                                   const __hip_bfloat16* __restrict__ Bw,
                                                   const float* __restrict__ bias,
                                                   float* __restrict__ xdbl,
                                                   __hip_bfloat16* __restrict__ delta) {
    __shared__ __align__(16) __hip_bfloat16 As[128*64];
    __shared__ __align__(16) __hip_bfloat16 Bs[128*64];
    const int K = 64;
    int tid = threadIdx.x, lane = tid & 63, w = tid >> 6;
    int gx = gridDim.x;
    int nwg = gx * gridDim.y;
    int orig = blockIdx.y*gx + blockIdx.x;
    int swz = (orig & 7)*(nwg >> 3) + (orig >> 3);
    int m0 = (swz / gx) * 128, n0 = (swz % gx) * 128;
    int wr = w >> 1, wc = w & 1;
    int kq = lane >> 4, rr = lane & 15;

    f32x4 acc[4][4];
    #pragma unroll
    for (int i = 0; i < 4; i++)
        #pragma unroll
        for (int j = 0; j < 4; j++) acc[i][j] = (f32x4){0.f,0.f,0.f,0.f};

    const char* Bb = (const char*)Bw;
    char* AsB = (char*)As;
    char* BsB = (char*)Bs;

    #pragma unroll
    for (int c = 0; c < 4; c++) {
        int idx = c*256 + tid;
        int r = idx >> 3, q = idx & 7;
        int qs = q ^ (r & 7);
        glds16(Bb + ((size_t)(n0+r)*K + qs*8)*2, BsB + idx*16);
    }

    const size_t RX = (size_t)ROWS*XN;
    #pragma unroll
    for (int it = 0; it < 2; it++) {
        int idx = it*1024 + tid;
        if (idx < 128*10) {
            int row = idx / 10, ch = idx % 10;
            const float* p0 = P + (size_t)(m0+row)*XN + ch*8;
            f32x4 a0 = *(const f32x4*)(p0)      + *(const f32x4*)(p0+RX)
                     + *(const f32x4*)(p0+2*RX) + *(const f32x4*)(p0+3*RX);
            f32x4 a1 = *(const f32x4*)(p0+4)        + *(const f32x4*)(p0+RX+4)
                     + *(const f32x4*)(p0+2*RX+4)   + *(const f32x4*)(p0+3*RX+4);
            if (n0 == 0) {
                float* xd = xdbl + (size_t)(m0+row)*XN + ch*8;
                *(f32x4*)(xd)   = a0;
                *(f32x4*)(xd+4) = a1;
            }
            if (ch < 8) {
                bf16x8 hv;
                if (ch < 6) {
                    #pragma unroll
                    for (int j = 0; j < 4; j++) { hv[j] = (__bf16)a0[j]; hv[4+j] = (__bf16)a1[j]; }
                } else {
                    bf16x8 z = {}; hv = z;
                }
                *(bf16x8*)(AsB + row*128 + ((ch ^ (row & 7))*16)) = hv;
            }
        }
    }
    __syncthreads();

    #pragma unroll
    for (int kh = 0; kh < 2; kh++) {
        int ch = ((kh*4 + kq) ^ (rr & 7)) * 16;
        bf16x8 af[4], bfr[4];
        #pragma unroll
        for (int mi = 0; mi < 4; mi++) af[mi]  = *(const bf16x8*)(AsB + (wr*64 + mi*16 + rr)*128 + ch);
        #pragma unroll
        for (int ni = 0; ni < 4; ni++) bfr[ni] = *(const bf16x8*)(BsB + (wc*64 + ni*16 + rr)*128 + ch);
        #pragma unroll
        for (int mi = 0; mi < 4; mi++)
            #pragma unroll
            for (int ni = 0; ni < 4; ni++)
                acc[mi][ni] = __builtin_amdgcn_mfma_f32_16x16x32_bf16(af[mi], bfr[ni], acc[mi][ni], 0, 0, 0);
    }

    #pragma unroll
    for (int mi = 0; mi < 4; mi++) {
        #pragma unroll
        for (int ni = 0; ni < 4; ni++) {
            int row0 = m0 + wr*64 + mi*16;
            int col  = n0 + wc*64 + ni*16 + rr;
            __hip_bfloat16 d4[4];
            #pragma unroll
            for (int r = 0; r < 4; r++) {
                float v = acc[mi][ni][r] + bias[col];
                d4[r] = __float2bfloat16(softplusf(v));
            }
            *(uint2*)&delta[((size_t)(row0 >> 4)*D_INNER + col)*16 + kq*4] = *(uint2*)d4;
        }
    }
}

// ---------------------------------------------------------------- out_proj: h += ygate @ W^T (BM=128 BN=64, 3-ring, tail-correct)
__global__ __launch_bounds__(256) void gemm_outproj(const __hip_bfloat16* __restrict__ A,
                                                    const __hip_bfloat16* __restrict__ Bw,
                                                    float* __restrict__ C) {
    __shared__ __align__(16) __hip_bfloat16 As[3][128*32];   // 24 KB
    __shared__ __align__(16) __hip_bfloat16 Bs[3][64*32];    // 12 KB
    int tid = threadIdx.x, lane = tid & 63, w = tid >> 6;
    int gx = gridDim.x;                       // 12
    int nwg = gx * gridDim.y;                 // 384
    int orig = blockIdx.y*gx + blockIdx.x;
    int swz = (orig & 7)*(nwg >> 3) + (orig >> 3);
    int m0 = (swz / gx) * 128, n0 = (swz % gx) * 64;
    int wr = w >> 1, wc = w & 1;
    int kq = lane >> 4, rr = lane & 15;
    const int K = D_INNER;
    const int NK = K/32;                      // 48

    f32x4 acc[4][2];
    #pragma unroll
    for (int i = 0; i < 4; i++)
        #pragma unroll
        for (int j = 0; j < 2; j++) acc[i][j] = (f32x4){0.f,0.f,0.f,0.f};

    const char* Ab = (const char*)A;
    const char* Bb = (const char*)Bw;
    char* AsB = (char*)As;
    char* BsB = (char*)Bs;

    int cA0 = tid, cA1 = tid + 256;
    int rA0 = cA0 >> 2, qA0 = (cA0 & 3) ^ ((rA0 >> 1) & 3);
    int rA1 = cA1 >> 2, qA1 = (cA1 & 3) ^ ((rA1 >> 1) & 3);
    int rB = tid >> 2,  qB  = (tid & 3) ^ ((rB >> 1) & 3);
    int sw = (kq ^ ((rr >> 1) & 3)) * 16;

    auto stage = [&](int buf, int kt) {
        int k0 = kt*32;
        glds16(Ab + ((size_t)(m0+rA0)*K + k0 + qA0*8)*2, AsB + buf*8192 + cA0*16);
        glds16(Ab + ((size_t)(m0+rA1)*K + k0 + qA1*8)*2, AsB + buf*8192 + cA1*16);
        glds16(Bb + ((size_t)(n0+rB)*K + k0 + qB*8)*2,  BsB + buf*4096 + tid*16);
    };

    stage(0, 0);
    stage(1, 1);

    for (int k = 0; k < NK; k++) {
        int cur = k % 3;
        __builtin_amdgcn_s_barrier();
        if (k + 2 < NK) stage((k + 2) % 3, k + 2);
        if (k + 2 < NK)      asm volatile("s_waitcnt vmcnt(6)" ::: "memory");
        else if (k + 1 < NK) asm volatile("s_waitcnt vmcnt(3)" ::: "memory");
        else                 asm volatile("s_waitcnt vmcnt(0)" ::: "memory");
        __builtin_amdgcn_s_barrier();
        bf16x8 af[4], bfr[2];
        #pragma unroll
        for (int mi = 0; mi < 4; mi++) af[mi]  = *(const bf16x8*)(AsB + cur*8192 + (wr*64 + mi*16 + rr)*64 + sw);
        #pragma unroll
        for (int ni = 0; ni < 2; ni++) bfr[ni] = *(const bf16x8*)(BsB + cur*4096 + (wc*32 + ni*16 + rr)*64 + sw);
        __builtin_amdgcn_s_setprio(1);
        #pragma unroll
        for (int mi = 0; mi < 4; mi++)
            #pragma unroll
            for (int ni = 0; ni < 2; ni++)
                acc[mi][ni] = __builtin_amdgcn_mfma_f32_16x16x32_bf16(af[mi], bfr[ni], acc[mi][ni], 0, 0, 0);
        __builtin_amdgcn_s_setprio(0);
    }

    #pragma unroll
    for (int mi = 0; mi < 4; mi++) {
        #pragma unroll
        for (int ni = 0; ni < 2; ni++) {
            #pragma unroll
            for (int r = 0; r < 4; r++) {
                int row = m0 + wr*64 + mi*16 + kq*4 + r;
                int col = n0 + wc*32 + ni*16 + rr;
                size_t o = (size_t)row*D_MODEL + col;
                C[o] = acc[mi][ni][r] + C[o];   // h holds the residual
            }
        }
    }
}

// ---------------------------------------------------------------- xproj MFMA: partials, split-K (3-buffer ring)
__global__ __launch_bounds__(256) void gemm_xproj(const __hip_bfloat16* __restrict__ A,
                                                  const __hip_bfloat16* __restrict__ W,
                                                  float* __restrict__ P) {
    __shared__ __align__(16) __hip_bfloat16 As[3][64*64];
    __shared__ __align__(16) __hip_bfloat16 Bs[3][96*64];
    int tid = threadIdx.x, lane = tid & 63, w = tid >> 6;
    int m0 = blockIdx.x * 64;
    int k0 = blockIdx.y * (D_INNER / KSPLIT);
    int kq = lane >> 4, rr = lane & 15;
    const int NK = (D_INNER/KSPLIT)/64;       // 6
    f32x4 acc[5];
    #pragma unroll
    for (int i = 0; i < 5; i++) acc[i] = (f32x4){0.f,0.f,0.f,0.f};
    const char* Ab = (const char*)A;
    const char* Wb = (const char*)W;
    char* AsB = (char*)As;
    char* BsB = (char*)Bs;

    auto stage = [&](int buf, int it) {
        int kk = k0 + it*64;
        #pragma unroll
        for (int cA = 0; cA < 2; cA++) {
            int idx = cA*256 + tid;
            int r = idx >> 3, q = (idx & 7) ^ (r & 7);
            glds16(Ab + ((size_t)(m0+r)*D_INNER + kk + q*8)*2, AsB + buf*8192 + idx*16);
        }
        #pragma unroll
        for (int cB = 0; cB < 3; cB++) {
            int idx = cB*256 + tid;
            int r = idx >> 3, q = (idx & 7) ^ (r & 7);
            int rs = r < XN ? r : XN-1;
            glds16(Wb + ((size_t)rs*D_INNER + kk + q*8)*2, BsB + buf*12288 + idx*16);
        }
    };

    stage(0, 0);
    stage(1, 1);

    for (int it = 0; it < NK; it++) {
        int cur = it % 3;
        __builtin_amdgcn_s_barrier();
        if (it + 2 < NK) stage((it + 2) % 3, it + 2);
        if (it + 2 < NK)      asm volatile("s_waitcnt vmcnt(10)" ::: "memory");
        else if (it + 1 < NK) asm volatile("s_waitcnt vmcnt(5)" ::: "memory");
        else                  asm volatile("s_waitcnt vmcnt(0)" ::: "memory");
        __builtin_amdgcn_s_barrier();
        #pragma unroll
        for (int kh = 0; kh < 2; kh++) {
            bf16x8 a = *(const bf16x8*)(AsB + cur*8192 + (w*16 + rr)*128 + (((kh*4 + kq) ^ (rr & 7)))*16);
            #pragma unroll
            for (int ni = 0; ni < 5; ni++) {
                bf16x8 b = *(const bf16x8*)(BsB + cur*12288 + (ni*16 + rr)*128 + (((kh*4 + kq) ^ (rr & 7)))*16);
                acc[ni] = __builtin_amdgcn_mfma_f32_16x16x32_bf16(a, b, acc[ni], 0, 0, 0);
            }
        }
    }
    float* Cp = P + (size_t)blockIdx.y * ROWS * XN;
    #pragma unroll
    for (int ni = 0; ni < 5; ni++)
        #pragma unroll
        for (int r = 0; r < 4; r++) {
            int row = m0 + w*16 + kq*4 + r;
            int col = ni*16 + rr;
            Cp[(size_t)row*XN + col] = acc[ni][r];
        }
}

// ---------------------------------------------------------------- depthwise causal conv + SiLU (bf16 in/out, x8 vec)
__global__ __launch_bounds__(256) void dwconv_silu(const __hip_bfloat16* __restrict__ xs,
                                                   const float* __restrict__ cw,
                                                   const float* __restrict__ cb,
                                                   __hip_bfloat16* __restrict__ u_bf) {
    int idx = blockIdx.x*256 + threadIdx.x;
    int dg = idx % (D_INNER/8);
    int t  = idx / (D_INNER/8);
    if (t >= ROWS) return;
    int d0 = dg*8;
    int l = t & 511, b = t >> 9;
    bf16x8 rows[K_CONV];
    #pragma unroll
    for (int k = 0; k < K_CONV; k++) {
        int ll = l - (K_CONV-1) + k;
        if (ll >= 0) rows[k] = *(const bf16x8*)(xs + ((size_t)(b*LSEQ + ll))*D_INNER + d0);
        else { bf16x8 z = {}; rows[k] = z; }
    }
    bf16x8 outv;
    #pragma unroll
    for (int j = 0; j < 8; j++) {
        int d = d0 + j;
        const float4 w4 = *(const float4*)(cw + d*K_CONV);
        float acc = cb[d]
                  + (float)rows[0][j]*w4.x + (float)rows[1][j]*w4.y
                  + (float)rows[2][j]*w4.z + (float)rows[3][j]*w4.w;
        float v = acc / (1.f + __expf(-acc));
        outv[j] = (__bf16)v;
    }
    *(bf16x8*)(u_bf + (size_t)t*D_INNER + d0) = outv;
}

// ---------------------------------------------------------------- selective scan, 3-phase chunked (NC=16, CL=32)
__global__ __launch_bounds__(256) void scan_p1(const __hip_bfloat16* __restrict__ u,
                                               const __hip_bfloat16* __restrict__ delta_blk,
                                               const float* __restrict__ xdbl,
                                               const float* __restrict__ A_log,
                                               float* __restrict__ xfin,
                                               float* __restrict__ sumdlt) {
    int d = blockIdx.x*256 + threadIdx.x;
    int c = blockIdx.y, b = blockIdx.z;
    int l0 = c*CL;
    const float* al = A_log + d*N_STATE;
    bool fast = true;
    #pragma unroll
    for (int n = 0; n < N_STATE; n++)
        fast = fast && (fabsf(__expf(al[n]) - (float)(n+1)) < 1e-3f);
    float xs[N_STATE];
    #pragma unroll
    for (int n = 0; n < N_STATE; n++) xs[n] = 0.f;
    const __hip_bfloat16* pu = u + (size_t)(b*LSEQ + l0)*D_INNER + d;
    const float* pB = xdbl + (size_t)(b*LSEQ + l0)*XN + DT_RANK;
    float sd = 0.f;
    if (fast) {
        #pragma unroll
        for (int tt = 0; tt < 2; tt++) {
            const __hip_bfloat16* db = delta_blk + ((size_t)(b*NTILE + (l0>>4) + tt)*D_INNER + d)*16;
            bf16x8 d0 = *(const bf16x8*)db;
            bf16x8 d1 = *(const bf16x8*)(db + 8);
            #pragma unroll
            for (int i = 0; i < 16; i++) {
                float dlt = (float)(i < 8 ? d0[i] : d1[i-8]);
                float uu = __bfloat162float(*pu); pu += D_INNER;
                float du = dlt*uu;
                sd += dlt;
                float e1 = fexp2(-dlt*LOG2E);
                float e = e1;
                xs[0] = e*xs[0] + du*pB[0];
                #pragma unroll
                for (int n = 1; n < N_STATE; n++) {
                    e *= e1;
                    xs[n] = e*xs[n] + du*pB[n];
                }
                pB += XN;
            }
        }
    } else {
        #pragma unroll
        for (int tt = 0; tt < 2; tt++) {
            const __hip_bfloat16* db = delta_blk + ((size_t)(b*NTILE + (l0>>4) + tt)*D_INNER + d)*16;
            bf16x8 d0 = *(const bf16x8*)db;
            bf16x8 d1 = *(const bf16x8*)(db + 8);
            #pragma unroll
            for (int i = 0; i < 16; i++) {
                float dlt = (float)(i < 8 ? d0[i] : d1[i-8]);
                float uu = __bfloat162float(*pu); pu += D_INNER;
                float du = dlt*uu;
                sd += dlt;
                #pragma unroll
                for (int n = 0; n < N_STATE; n++) {
                    float A2n = -__expf(al[n]) * LOG2E;
                    xs[n] = fexp2(dlt*A2n)*xs[n] + du*pB[n];
                }
                pB += XN;
            }
        }
    }
    float* px = xfin + (size_t)((b*NC + c)*N_STATE)*D_INNER + d;
    #pragma unroll
    for (int n = 0; n < N_STATE; n++) px[n*D_INNER] = xs[n];
    sumdlt[(size_t)(b*NC + c)*D_INNER + d] = sd;
}

__global__ __launch_bounds__(256) void scan_p2(float* __restrict__ xfin,
                                               const float* __restrict__ sumdlt,
                                               const float* __restrict__ A_log) {
    int idx = blockIdx.x*256 + threadIdx.x;
    int d = idx % D_INNER;
    int r = idx / D_INNER;
    int n = r & 15;
    int b = r >> 4;
    float A2 = -__expf(A_log[d*N_STATE + n]) * LOG2E;
    float cr = 0.f;
    for (int c = 1; c < NC; c++) {
        size_t jp = (size_t)(b*NC + c - 1);
        float xf = xfin[(jp*N_STATE + n)*D_INNER + d];
        float s  = sumdlt[jp*D_INNER + d];
        cr = fexp2(A2 * s) * cr + xf;
        xfin[(jp*N_STATE + n)*D_INNER + d] = cr;
    }
}

__global__ __launch_bounds__(256) void scan_p3(const __hip_bfloat16* __restrict__ u,
                                               const __hip_bfloat16* __restrict__ delta_blk,
                                               const __hip_bfloat16* __restrict__ gres,
                                               const float* __restrict__ xdbl,
                                               const float* __restrict__ A_log,
                                               const float* __restrict__ Dp,
                                               const float* __restrict__ carry,
                                               __hip_bfloat16* __restrict__ ygate) {
    int d = blockIdx.x*256 + threadIdx.x;
    int c = blockIdx.y, b = blockIdx.z;
    int l0 = c*CL;
    const float* al = A_log + d*N_STATE;
    bool fast = true;
    #pragma unroll
    for (int n = 0; n < N_STATE; n++)
        fast = fast && (fabsf(__expf(al[n]) - (float)(n+1)) < 1e-3f);
    float xs[N_STATE];
    if (c == 0) {
        #pragma unroll
        for (int n = 0; n < N_STATE; n++) xs[n] = 0.f;
    } else {
        const float* pc = carry + (size_t)((b*NC + c - 1)*N_STATE)*D_INNER + d;
        #pragma unroll
        for (int n = 0; n < N_STATE; n++) xs[n] = pc[n*D_INNER];
    }
    float Dv = Dp[d];
    const __hip_bfloat16* pu = u + (size_t)(b*LSEQ + l0)*D_INNER + d;
    const float* pB = xdbl + (size_t)(b*LSEQ + l0)*XN + DT_RANK;
    __hip_bfloat16* py = ygate + (size_t)(b*LSEQ + l0)*D_INNER + d;
    if (fast) {
        #pragma unroll
        for (int tt = 0; tt < 2; tt++) {
            size_t tb = (size_t)(b*NTILE + (l0>>4) + tt)*D_INNER + d;
            const __hip_bfloat16* db = delta_blk + tb*16;
            bf16x8 d0 = *(const bf16x8*)db;
            bf16x8 d1 = *(const bf16x8*)(db + 8);
            const __hip_bfloat16* gb = gres + tb*16;
            bf16x8 g0 = *(const bf16x8*)gb;
            bf16x8 g1 = *(const bf16x8*)(gb + 8);
            #pragma unroll
            for (int i = 0; i < 16; i++) {
                float dlt = (float)(i < 8 ? d0[i] : d1[i-8]);
                float gr  = (float)(i < 8 ? g0[i] : g1[i-8]);
                float uu = __bfloat162float(*pu); pu += D_INNER;
                float du = dlt*uu;
                float e1 = fexp2(-dlt*LOG2E);
                float e = e1;
                float acc;
                xs[0] = e*xs[0] + du*pB[0];
                acc = xs[0]*pB[N_STATE + 0];
                #pragma unroll
                for (int n = 1; n < N_STATE; n++) {
                    e *= e1;
                    xs[n] = e*xs[n] + du*pB[n];
                    acc += xs[n]*pB[N_STATE + n];
                }
                pB += XN;
                float y = acc + uu*Dv;
                *py = __float2bfloat16(y * gr); py += D_INNER;
            }
        }
    } else {
        #pragma unroll
        for (int tt = 0; tt < 2; tt++) {
            size_t tb = (size_t)(b*NTILE + (l0>>4) + tt)*D_INNER + d;
            const __hip_bfloat16* db = delta_blk + tb*16;
            bf16x8 d0 = *(const bf16x8*)db;
            bf16x8 d1 = *(const bf16x8*)(db + 8);
            const __hip_bfloat16* gb = gres + tb*16;
            bf16x8 g0 = *(const bf16x8*)gb;
            bf16x8 g1 = *(const bf16x8*)(gb + 8);
            #pragma unroll
            for (int i = 0; i < 16; i++) {
                float dlt = (float)(i < 8 ? d0[i] : d1[i-8]);
                float gr  = (float)(i < 8 ? g0[i] : g1[i-8]);
                float uu = __bfloat162float(*pu); pu += D_INNER;
                float du = dlt*uu;
                float acc = 0.f;
                #pragma unroll
                for (int n = 0; n < N_STATE; n++) {
                    float A2n = -__expf(al[n]) * LOG2E;
                    xs[n] = fexp2(dlt*A2n)*xs[n] + du*pB[n];
                    acc += xs[n]*pB[N_STATE + n];
                }
                pB += XN;
                float y = acc + uu*Dv;
                *py = __float2bfloat16(y * gr); py += D_INNER;
            }
        }
    }
}

// ---------------------------------------------------------------- final norm + head + de-norm
__global__ __launch_bounds__(256) void final_kernel(const float* __restrict__ h,
                                                    const float* __restrict__ fnw,
                                                    const float* __restrict__ out_w,
                                                    const float* __restrict__ mean,
                                                    const float* __restrict__ stdv,
                                                    float* __restrict__ out) {
    int bid = blockIdx.x;
    int b = bid / PRED_LEN, lo = bid % PRED_LEN;
    int l = LSEQ - PRED_LEN + lo;
    const float* row = h + ((size_t)(b*LSEQ + l))*D_MODEL;
    __shared__ float tmp[4];
    float ss = 0.f;
    for (int k = threadIdx.x; k < D_MODEL; k += 256) { float v = row[k]; ss += v*v; }
    ss = block_sum(ss, tmp);
    float inv = rsqrtf(ss / (float)D_MODEL + EPSV);
    float acc[C_OUT] = {};
    for (int k = threadIdx.x; k < D_MODEL; k += 256) {
        float hn = row[k]*fnw[k];
        #pragma unroll
        for (int c = 0; c < C_OUT; c++) acc[c] += hn*out_w[c*D_MODEL + k];
    }
    #pragma unroll
    for (int c = 0; c < C_OUT; c++) {
        float s = block_sum(acc[c], tmp);
        if (threadIdx.x == 0)
            out[((size_t)(b*PRED_LEN + lo))*C_OUT + c] = s*inv*stdv[b*ENC_IN + c] + mean[b*ENC_IN + c];
    }
}

// ---------------------------------------------------------------- launch
extern "C" void kernel_launch(void* const* d_in, const int* in_sizes, int n_in,
                              void* d_out, int out_size, void* d_ws, size_t ws_size,
                              hipStream_t stream) {
    const float* x        = (const float*)d_in[0];
    const float* token_w  = (const float*)d_in[1];
    const float* time_w   = (const float*)d_in[2];
    const float* norm_w   = (const float*)d_in[3];
    const float* in_w     = (const float*)d_in[4];
    const float* conv_w   = (const float*)d_in[5];
    const float* conv_b   = (const float*)d_in[6];
    const float* xproj_w  = (const float*)d_in[7];
    const float* dtproj_w = (const float*)d_in[8];
    const float* dtproj_b = (const float*)d_in[9];
    const float* A_log    = (const float*)d_in[10];
    const float* Dp       = (const float*)d_in[11];
    const float* outproj_w= (const float*)d_in[12];
    const float* final_nw = (const float*)d_in[13];
    const float* out_w    = (const float*)d_in[14];
    float* out = (float*)d_out;

    float* ws   = (float*)d_ws;
    float* mean = ws;
    float* stdv = ws + 64;
    float* h    = ws + 128;                            // ROWS*D_MODEL
    float* xdbl = h    + (size_t)ROWS*D_MODEL;         // ROWS*80 f32
    float* sumd = xdbl + (size_t)ROWS*XN;              // BSZ*NC*D_INNER
    float* xfin = sumd + (size_t)BSZ*NC*D_INNER;       // BSZ*NC*N_STATE*D_INNER
    float* pout = xfin + (size_t)BSZ*NC*D_INNER*N_STATE; // KSPLIT*ROWS*XN partials
    float* fend = pout + (size_t)KSPLIT*ROWS*XN;
    __hip_bfloat16* xn_bf  = (__hip_bfloat16*)fend;
    __hip_bfloat16* xs_bf  = xn_bf + (size_t)ROWS*D_MODEL;
    __hip_bfloat16* u_bf   = xs_bf + (size_t)ROWS*D_INNER;
    __hip_bfloat16* gres   = u_bf  + (size_t)ROWS*D_INNER;
    __hip_bfloat16* ygate  = gres  + (size_t)ROWS*D_INNER;
    __hip_bfloat16* delta  = ygate + (size_t)ROWS*D_INNER;
    __hip_bfloat16* inw_bf = delta + (size_t)ROWS*D_INNER;
    __hip_bfloat16* outw_bf= inw_bf + (size_t)E_LAYERS*2*D_INNER*D_MODEL;
    __hip_bfloat16* xpw_bf = outw_bf+ (size_t)E_LAYERS*D_MODEL*D_INNER;
    __hip_bfloat16* dtw_bf = xpw_bf + (size_t)E_LAYERS*XN*D_INNER;

    {
        const int NT = E_LAYERS*2*D_INNER*D_MODEL + E_LAYERS*D_MODEL*D_INNER
                     + E_LAYERS*XN*D_INNER + E_LAYERS*D_INNER*64;
        cvt_all<<<(NT+255)/256, 256, 0, stream>>>(in_w, outproj_w, xproj_w, dtproj_w,
                                                  inw_bf, outw_bf, xpw_bf, dtw_bf);
    }

    stats_kernel<<<BSZ*ENC_IN, 256, 0, stream>>>(x, mean, stdv);
    embed_kernel<<<ROWS, 256, 0, stream>>>(x, token_w, time_w, mean, stdv, h);

    for (int e = 0; e < E_LAYERS; e++) {
        rmsnorm_bf16<<<ROWS, 256, 0, stream>>>(h, norm_w + e*D_MODEL, xn_bf);
        gemm_inproj<<<dim3(2*D_INNER/128, ROWS/128), 256, 0, stream>>>(
            xn_bf, inw_bf + (size_t)e*2*D_INNER*D_MODEL, xs_bf, gres);
        dwconv_silu<<<(ROWS*(D_INNER/8) + 255)/256, 256, 0, stream>>>(
            xs_bf, conv_w + (size_t)e*D_INNER*K_CONV, conv_b + e*D_INNER, u_bf);
        gemm_xproj<<<dim3(ROWS/64, KSPLIT), 256, 0, stream>>>(
            u_bf, xpw_bf + (size_t)e*XN*D_INNER, pout);
        gemm_dtproj<<<dim3(D_INNER/128, ROWS/128), 256, 0, stream>>>(
            pout, dtw_bf + (size_t)e*D_INNER*64, dtproj_b + e*D_INNER, xdbl, delta);
        const float* Alog_e = A_log + (size_t)e*D_INNER*N_STATE;
        scan_p1<<<dim3(D_INNER/256, NC, BSZ), 256, 0, stream>>>(
            u_bf, delta, xdbl, Alog_e, xfin, sumd);
        scan_p2<<<(BSZ*D_INNER*N_STATE)/256, 256, 0, stream>>>(
            xfin, sumd, Alog_e);
        scan_p3<<<dim3(D_INNER/256, NC, BSZ), 256, 0, stream>>>(
            u_bf, delta, gres, xdbl, Alog_e, Dp + (size_t)e*D_INNER, xfin, ygate);
        gemm_outproj<<<dim3(D_MODEL/64, ROWS/128), 256, 0, stream>>>(
            ygate, outw_bf + (size_t)e*D_MODEL*D_INNER, h);
    }

    final_kernel<<<BSZ*PRED_LEN, 256, 0, stream>>>(h, final_nw, out_w, mean, stdv, out);
}

// Round 15
// 376.112 us; speedup vs baseline: 1.0682x; 1.0122x over previous
//
#include <hip/hip_runtime.h>
#include <hip/hip_bf16.h>
#include <math.h>

// Problem constants
#define BSZ 8
#define LSEQ 512
#define ENC_IN 7
#define D_MODEL 768
#define D_INNER 1536
#define DT_RANK 48
#define N_STATE 16
#define K_CONV 4
#define E_LAYERS 2
#define C_OUT 7
#define PRED_LEN 96
#define EPSV 1e-5f
#define XN 80
#define KSPLIT 4

#define ROWS (BSZ*LSEQ)            // 4096
#define NC 16                      // scan chunks
#define CL (LSEQ/NC)               // 32 steps per chunk
#define NTILE (LSEQ/16)            // 32 16-step tiles per batch
#define LOG2E 1.44269504088896f
// packed in_w geometry: 24 panels x 24 ksteps x 8 frags x 64 lanes x 8 elems
#define INP_PANELS (2*D_INNER/128)     // 24
#define INP_KSTEPS (D_MODEL/32)        // 24
#define INP_LAYER  (INP_PANELS*INP_KSTEPS*8*64*8)   // 2359296 == 3072*768

typedef __bf16 bf16x8 __attribute__((ext_vector_type(8)));
typedef float  f32x4  __attribute__((ext_vector_type(4)));

// raw hardware exp2 (single v_exp_f32)
__device__ __forceinline__ float fexp2(float x) {
    float r;
    asm("v_exp_f32 %0, %1" : "=v"(r) : "v"(x));
    return r;
}
__device__ __forceinline__ float softplusf(float v) {
    return fmaxf(v, 0.f) + log1pf(__expf(-fabsf(v)));
}
__device__ __forceinline__ void glds16(const char* g, char* l) {
    __builtin_amdgcn_global_load_lds((const __attribute__((address_space(1))) unsigned int*)g,
                                     (__attribute__((address_space(3))) unsigned int*)l, 16, 0, 0);
}

// ---------------------------------------------------------------- utilities
__device__ __forceinline__ float block_sum(float v, float* tmp) {
    #pragma unroll
    for (int off = 32; off > 0; off >>= 1) v += __shfl_down(v, off);
    int lane = threadIdx.x & 63, wid = threadIdx.x >> 6;
    __syncthreads();
    if (lane == 0) tmp[wid] = v;
    __syncthreads();
    return tmp[0] + tmp[1] + tmp[2] + tmp[3];
}

// ---------------------------------------------------------------- weight conversion (row-major bf16 for outw/xpw/dtw)
__global__ __launch_bounds__(256) void cvt_all(const float* __restrict__ outw,
                                               const float* __restrict__ xpw,
                                               const float* __restrict__ dtw,
                                               __hip_bfloat16* __restrict__ outw_bf,
                                               __hip_bfloat16* __restrict__ xpw_bf,
                                               __hip_bfloat16* __restrict__ dtw_bf) {
    const int N2 = E_LAYERS*D_MODEL*D_INNER;
    const int N3 = E_LAYERS*XN*D_INNER;
    const int N4 = E_LAYERS*D_INNER*64;
    int i = blockIdx.x*256 + threadIdx.x;
    if (i < N2) {
        outw_bf[i] = __float2bfloat16(outw[i]);
    } else if (i < N2+N3) {
        int j = i - N2; xpw_bf[j] = __float2bfloat16(xpw[j]);
    } else if (i < N2+N3+N4) {
        int j = i - N2 - N3;
        int r = j >> 6, c = j & 63;
        dtw_bf[j] = __float2bfloat16(c < DT_RANK ? dtw[r*DT_RANK + c] : 0.f);
    }
}

// pack in_w (f32 [2*D_INNER][D_MODEL]) -> fragment-linear bf16
// dst[((p*24 + k)*8 + f)*512 + l*8 + e] = in_w[p*128 + f*16 + (l&15)][k*32 + (l>>4)*8 + e]
__global__ __launch_bounds__(256) void pack_inw(const float* __restrict__ src,
                                                __hip_bfloat16* __restrict__ dst) {
    int i = blockIdx.x*256 + threadIdx.x;          // one thread = 8 elems
    const int PER_LAYER = INP_LAYER/8;             // 294912
    if (i >= E_LAYERS*PER_LAYER) return;
    int e2 = i / PER_LAYER;
    int r  = i % PER_LAYER;                        // ((p*24 + k)*8 + f)*64 + l
    int l  = r & 63;
    int pf = r >> 6;                               // (p*24 + k)*8 + f
    int f  = pf & 7;
    int pk = pf >> 3;
    int k  = pk % INP_KSTEPS;
    int p  = pk / INP_KSTEPS;
    int row = p*128 + f*16 + (l & 15);
    int col = k*32 + (l >> 4)*8;
    const float* s = src + (size_t)e2*2*D_INNER*D_MODEL + (size_t)row*D_MODEL + col;
    __hip_bfloat16 o8[8];
    #pragma unroll
    for (int e = 0; e < 8; e++) o8[e] = __float2bfloat16(s[e]);
    *(uint4*)(dst + (size_t)e2*INP_LAYER + (size_t)r*8) = *(uint4*)o8;
}

// ---------------------------------------------------------------- stats (RevIN)
__global__ __launch_bounds__(256) void stats_kernel(const float* __restrict__ x,
                                                    float* __restrict__ mean,
                                                    float* __restrict__ stdv) {
    int bc = blockIdx.x;
    int b = bc / ENC_IN, c = bc % ENC_IN;
    __shared__ float tmp[4];
    float s = 0.f, sq = 0.f;
    for (int l = threadIdx.x; l < LSEQ; l += 256) {
        float v = x[((size_t)(b*LSEQ + l))*ENC_IN + c];
        s += v; sq += v*v;
    }
    s = block_sum(s, tmp);
    sq = block_sum(sq, tmp);
    if (threadIdx.x == 0) {
        float m = s / LSEQ;
        float var = sq / LSEQ - m*m;
        if (var < 0.f) var = 0.f;
        mean[bc] = m;
        stdv[bc] = sqrtf(var + EPSV);
    }
}

// ---------------------------------------------------------------- embedding
__global__ __launch_bounds__(256) void embed_kernel(const float* __restrict__ x,
                                                    const float* __restrict__ token_w,
                                                    const float* __restrict__ time_w,
                                                    const float* __restrict__ mean,
                                                    const float* __restrict__ stdv,
                                                    float* __restrict__ h) {
    int bl = blockIdx.x;
    int b = bl >> 9, l = bl & 511;
    __shared__ float sxc[ENC_IN*3];
    if (threadIdx.x < ENC_IN*3) {
        int c = threadIdx.x / 3, k = threadIdx.x % 3;
        int lk = (l + k - 1) & 511;
        float v = x[((size_t)(b*LSEQ + lk))*ENC_IN + c];
        sxc[threadIdx.x] = (v - mean[b*ENC_IN + c]) / stdv[b*ENC_IN + c];
    }
    __syncthreads();
    #pragma unroll
    for (int i = 0; i < 3; i++) {
        int d = threadIdx.x + i*256;
        float acc = 0.f;
        const float* w = token_w + (size_t)d*21;
        #pragma unroll
        for (int t = 0; t < 21; t++) acc += sxc[t] * w[t];
        int d2 = d & ~1;
        float div = __expf((float)d2 * (-9.210340371976184f / (float)D_MODEL));
        float ang = (float)l * div;
        float pe = (d & 1) ? cosf(ang) : sinf(ang);
        float tm = ((float)l / (float)LSEQ) * time_w[d];
        h[(size_t)bl*D_MODEL + d] = acc + pe + tm;
    }
}

// ---------------------------------------------------------------- rmsnorm -> bf16 (vectorized)
__global__ __launch_bounds__(256) void rmsnorm_bf16(const float* __restrict__ h,
                                                    const float* __restrict__ w,
                                                    __hip_bfloat16* __restrict__ xn) {
    size_t base = (size_t)blockIdx.x * D_MODEL;
    __shared__ float tmp[4];
    int tid = threadIdx.x;
    f32x4 v = {0.f,0.f,0.f,0.f};
    if (tid < 192) v = *(const f32x4*)(h + base + tid*4);
    float ss = v[0]*v[0] + v[1]*v[1] + v[2]*v[2] + v[3]*v[3];
    ss = block_sum(ss, tmp);
    float inv = rsqrtf(ss / (float)D_MODEL + EPSV);
    if (tid < 192) {
        f32x4 wv = *(const f32x4*)(w + tid*4);
        __hip_bfloat16 o4[4];
        #pragma unroll
        for (int j = 0; j < 4; j++) o4[j] = __float2bfloat16(v[j]*inv*wv[j]);
        *(uint2*)(xn + base + tid*4) = *(uint2*)o4;
    }
}

// ---------------------------------------------------------------- in_proj MFMA GEMM (BM=128 x BN=128, BK=32)
// A staged via 3-ring global_load_lds; B read DIRECT from fragment-packed global (L2-resident),
// register double-buffered one K-step ahead. LDS = A only (24 KB).
__global__ __launch_bounds__(256) void gemm_inproj(const __hip_bfloat16* __restrict__ A,
                                                   const __hip_bfloat16* __restrict__ Bp,
                                                   __hip_bfloat16* __restrict__ Cxs,
                                                   __hip_bfloat16* __restrict__ Cg) {
    __shared__ __align__(16) __hip_bfloat16 As[3][128*32];   // 24 KB
    const int K = D_MODEL;
    const int NK = K/32;                                     // 24
    int tid = threadIdx.x, lane = tid & 63, w = tid >> 6;
    int gx = gridDim.x;                                      // 24
    int nwg = gx * gridDim.y;                                // 768
    int orig = blockIdx.y*gx + blockIdx.x;
    int swz = (orig & 7)*(nwg >> 3) + (orig >> 3);
    int m0 = (swz / gx) * 128;
    int pn = (swz % gx);                                     // B panel index
    int wr = w >> 1, wc = w & 1;
    int kq = lane >> 4, rr = lane & 15;

    f32x4 acc[4][4];
    #pragma unroll
    for (int i = 0; i < 4; i++)
        #pragma unroll
        for (int j = 0; j < 4; j++) acc[i][j] = (f32x4){0.f,0.f,0.f,0.f};

    const char* Ab = (const char*)A;
    char* AsB = (char*)As;

    int c0 = tid, c1 = tid + 256;
    int r0 = c0 >> 2, q0 = (c0 & 3) ^ ((r0 >> 1) & 3);
    int r1 = c1 >> 2, q1 = (c1 & 3) ^ ((r1 >> 1) & 3);
    int sw = (kq ^ ((rr >> 1) & 3)) * 16;

    auto stageA = [&](int buf, int kt) {
        int k0 = kt*32;
        glds16(Ab + ((size_t)(m0+r0)*K + k0 + q0*8)*2, AsB + buf*8192 + c0*16);
        glds16(Ab + ((size_t)(m0+r1)*K + k0 + q1*8)*2, AsB + buf*8192 + c1*16);
    };
    // B fragment base for (panel pn, wave-col wc, lane): + kt*8*512 walks ksteps
    const __hip_bfloat16* Bbase = Bp + ((size_t)pn*INP_KSTEPS*8 + wc*4)*512 + lane*8;

    bf16x8 bcur[4], bnxt[4];
    stageA(0, 0);
    stageA(1, 1);
    #pragma unroll
    for (int ni = 0; ni < 4; ni++) bcur[ni] = *(const bf16x8*)(Bbase + ni*512);

    for (int k = 0; k < NK; k++) {
        int cur = k % 3;
        __builtin_amdgcn_s_barrier();                 // all waves done reading buf being overwritten
        if (k + 2 < NK) stageA((k + 2) % 3, k + 2);
        if (k + 1 < NK) {
            const __hip_bfloat16* bp = Bbase + (size_t)(k + 1)*8*512;
            #pragma unroll
            for (int ni = 0; ni < 4; ni++) bnxt[ni] = *(const bf16x8*)(bp + ni*512);
        }
        // A(cur) staged 2 iters ago; newer VMEM: 2x(2 A-stage + 4 B-loads) = 12
        if (k + 2 < NK) asm volatile("s_waitcnt vmcnt(12)" ::: "memory");
        else            asm volatile("s_waitcnt vmcnt(0)" ::: "memory");
        __builtin_amdgcn_s_barrier();                 // cur ready for all waves
        bf16x8 af[4];
        #pragma unroll
        for (int mi = 0; mi < 4; mi++) af[mi] = *(const bf16x8*)(AsB + cur*8192 + (wr*64 + mi*16 + rr)*64 + sw);
        __builtin_amdgcn_s_setprio(1);
        #pragma unroll
        for (int mi = 0; mi < 4; mi++)
            #pragma unroll
            for (int ni = 0; ni < 4; ni++)
                acc[mi][ni] = __builtin_amdgcn_mfma_f32_16x16x32_bf16(af[mi], bcur[ni], acc[mi][ni], 0, 0, 0);
        __builtin_amdgcn_s_setprio(0);
        #pragma unroll
        for (int ni = 0; ni < 4; ni++) bcur[ni] = bnxt[ni];
    }

    int n0 = pn * 128;
    #pragma unroll
    for (int mi = 0; mi < 4; mi++) {
        #pragma unroll
        for (int ni = 0; ni < 4; ni++) {
            int row0 = m0 + wr*64 + mi*16;
            int col  = n0 + wc*64 + ni*16 + rr;
            if (col >= D_INNER) {
                __hip_bfloat16 g4[4];
                #pragma unroll
                for (int r = 0; r < 4; r++) {
                    float v = acc[mi][ni][r];
                    g4[r] = __float2bfloat16(v / (1.f + __expf(-v)));   // silu
                }
                int cd = col - D_INNER;
                *(uint2*)&Cg[((size_t)(row0 >> 4)*D_INNER + cd)*16 + kq*4] = *(uint2*)g4;
            } else {
                #pragma unroll
                for (int r = 0; r < 4; r++) {
                    int row = row0 + kq*4 + r;
                    Cxs[(size_t)row*D_INNER + col] = __float2bfloat16(acc[mi][ni][r]);
                }
            }
        }
    }
}

// ---------------------------------------------------------------- dtproj MFMA (K=64, fused split-K reduction of pout)
__global__ __launch_bounds__(256) void gemm_dtproj(const float* __restrict__ P,
                                                   const __hip_bfloat16* __restrict__ Bw,
                                                   const float* __restrict__ bias,
                                                   float* __restrict__ xdbl,
                                                   __hip_bfloat16* __restrict__ delta) {
    __shared__ __align__(16) __hip_bfloat16 As[128*64];
    __shared__ __align__(16) __hip_bfloat16 Bs[128*64];
    const int K = 64;
    int tid = threadIdx.x, lane = tid & 63, w = tid >> 6;
    int gx = gridDim.x;
    int nwg = gx * gridDim.y;
    int orig = blockIdx.y*gx + blockIdx.x;
    int swz = (orig & 7)*(nwg >> 3) + (orig >> 3);
    int m0 = (swz / gx) * 128, n0 = (swz % gx) * 128;
    int wr = w >> 1, wc = w & 1;
    int kq = lane >> 4, rr = lane & 15;

    f32x4 acc[4][4];
    #pragma unroll
    for (int i = 0; i < 4; i++)
        #pragma unroll
        for (int j = 0; j < 4; j++) acc[i][j] = (f32x4){0.f,0.f,0.f,0.f};

    const char* Bb = (const char*)Bw;
    char* AsB = (char*)As;
    char* BsB = (char*)Bs;

    #pragma unroll
    for (int c = 0; c < 4; c++) {
        int idx = c*256 + tid;
        int r = idx >> 3, q = idx & 7;
        int qs = q ^ (r & 7);
        glds16(Bb + ((size_t)(n0+r)*K + qs*8)*2, BsB + idx*16);
    }

    const size_t RX = (size_t)ROWS*XN;
    #pragma unroll
    for (int it = 0; it < 2; it++) {
        int idx = it*1024 + tid;
        if (idx < 128*10) {
            int row = idx / 10, ch = idx % 10;
            const float* p0 = P + (size_t)(m0+row)*XN + ch*8;
            f32x4 a0 = *(const f32x4*)(p0)      + *(const f32x4*)(p0+RX)
                     + *(const f32x4*)(p0+2*RX) + *(const f32x4*)(p0+3*RX);
            f32x4 a1 = *(const f32x4*)(p0+4)        + *(const f32x4*)(p0+RX+4)
                     + *(const f32x4*)(p0+2*RX+4)   + *(const f32x4*)(p0+3*RX+4);
            if (n0 == 0) {
                float* xd = xdbl + (size_t)(m0+row)*XN + ch*8;
                *(f32x4*)(xd)   = a0;
                *(f32x4*)(xd+4) = a1;
            }
            if (ch < 8) {
                bf16x8 hv;
                if (ch < 6) {
                    #pragma unroll
                    for (int j = 0; j < 4; j++) { hv[j] = (__bf16)a0[j]; hv[4+j] = (__bf16)a1[j]; }
                } else {
                    bf16x8 z = {}; hv = z;
                }
                *(bf16x8*)(AsB + row*128 + ((ch ^ (row & 7))*16)) = hv;
            }
        }
    }
    __syncthreads();

    #pragma unroll
    for (int kh = 0; kh < 2; kh++) {
        int ch = ((kh*4 + kq) ^ (rr & 7)) * 16;
        bf16x8 af[4], bfr[4];
        #pragma unroll
        for (int mi = 0; mi < 4; mi++) af[mi]  = *(const bf16x8*)(AsB + (wr*64 + mi*16 + rr)*128 + ch);
        #pragma unroll
        for (int ni = 0; ni < 4; ni++) bfr[ni] = *(const bf16x8*)(BsB + (wc*64 + ni*16 + rr)*128 + ch);
        #pragma unroll
        for (int mi = 0; mi < 4; mi++)
            #pragma unroll
            for (int ni = 0; ni < 4; ni++)
                acc[mi][ni] = __builtin_amdgcn_mfma_f32_16x16x32_bf16(af[mi], bfr[ni], acc[mi][ni], 0, 0, 0);
    }

    #pragma unroll
    for (int mi = 0; mi < 4; mi++) {
        #pragma unroll
        for (int ni = 0; ni < 4; ni++) {
            int row0 = m0 + wr*64 + mi*16;
            int col  = n0 + wc*64 + ni*16 + rr;
            __hip_bfloat16 d4[4];
            #pragma unroll
            for (int r = 0; r < 4; r++) {
                float v = acc[mi][ni][r] + bias[col];
                d4[r] = __float2bfloat16(softplusf(v));
            }
            *(uint2*)&delta[((size_t)(row0 >> 4)*D_INNER + col)*16 + kq*4] = *(uint2*)d4;
        }
    }
}

// ---------------------------------------------------------------- out_proj: h += ygate @ W^T (BM=128 BN=64, 3-ring, tail-correct)
__global__ __launch_bounds__(256) void gemm_outproj(const __hip_bfloat16* __restrict__ A,
                                                    const __hip_bfloat16* __restrict__ Bw,
                                                    float* __restrict__ C) {
    __shared__ __align__(16) __hip_bfloat16 As[3][128*32];   // 24 KB
    __shared__ __align__(16) __hip_bfloat16 Bs[3][64*32];    // 12 KB
    int tid = threadIdx.x, lane = tid & 63, w = tid >> 6;
    int gx = gridDim.x;                       // 12
    int nwg = gx * gridDim.y;                 // 384
    int orig = blockIdx.y*gx + blockIdx.x;
    int swz = (orig & 7)*(nwg >> 3) + (orig >> 3);
    int m0 = (swz / gx) * 128, n0 = (swz % gx) * 64;
    int wr = w >> 1, wc = w & 1;
    int kq = lane >> 4, rr = lane & 15;
    const int K = D_INNER;
    const int NK = K/32;                      // 48

    f32x4 acc[4][2];
    #pragma unroll
    for (int i = 0; i < 4; i++)
        #pragma unroll
        for (int j = 0; j < 2; j++) acc[i][j] = (f32x4){0.f,0.f,0.f,0.f};

    const char* Ab = (const char*)A;
    const char* Bb = (const char*)Bw;
    char* AsB = (char*)As;
    char* BsB = (char*)Bs;

    int cA0 = tid, cA1 = tid + 256;
    int rA0 = cA0 >> 2, qA0 = (cA0 & 3) ^ ((rA0 >> 1) & 3);
    int rA1 = cA1 >> 2, qA1 = (cA1 & 3) ^ ((rA1 >> 1) & 3);
    int rB = tid >> 2,  qB  = (tid & 3) ^ ((rB >> 1) & 3);
    int sw = (kq ^ ((rr >> 1) & 3)) * 16;

    auto stage = [&](int buf, int kt) {
        int k0 = kt*32;
        glds16(Ab + ((size_t)(m0+rA0)*K + k0 + qA0*8)*2, AsB + buf*8192 + cA0*16);
        glds16(Ab + ((size_t)(m0+rA1)*K + k0 + qA1*8)*2, AsB + buf*8192 + cA1*16);
        glds16(Bb + ((size_t)(n0+rB)*K + k0 + qB*8)*2,  BsB + buf*4096 + tid*16);
    };

    stage(0, 0);
    stage(1, 1);

    for (int k = 0; k < NK; k++) {
        int cur = k % 3;
        __builtin_amdgcn_s_barrier();
        if (k + 2 < NK) stage((k + 2) % 3, k + 2);
        if (k + 2 < NK)      asm volatile("s_waitcnt vmcnt(6)" ::: "memory");
        else if (k + 1 < NK) asm volatile("s_waitcnt vmcnt(3)" ::: "memory");
        else                 asm volatile("s_waitcnt vmcnt(0)" ::: "memory");
        __builtin_amdgcn_s_barrier();
        bf16x8 af[4], bfr[2];
        #pragma unroll
        for (int mi = 0; mi < 4; mi++) af[mi]  = *(const bf16x8*)(AsB + cur*8192 + (wr*64 + mi*16 + rr)*64 + sw);
        #pragma unroll
        for (int ni = 0; ni < 2; ni++) bfr[ni] = *(const bf16x8*)(BsB + cur*4096 + (wc*32 + ni*16 + rr)*64 + sw);
        __builtin_amdgcn_s_setprio(1);
        #pragma unroll
        for (int mi = 0; mi < 4; mi++)
            #pragma unroll
            for (int ni = 0; ni < 2; ni++)
                acc[mi][ni] = __builtin_amdgcn_mfma_f32_16x16x32_bf16(af[mi], bfr[ni], acc[mi][ni], 0, 0, 0);
        __builtin_amdgcn_s_setprio(0);
    }

    #pragma unroll
    for (int mi = 0; mi < 4; mi++) {
        #pragma unroll
        for (int ni = 0; ni < 2; ni++) {
            #pragma unroll
            for (int r = 0; r < 4; r++) {
                int row = m0 + wr*64 + mi*16 + kq*4 + r;
                int col = n0 + wc*32 + ni*16 + rr;
                size_t o = (size_t)row*D_MODEL + col;
                C[o] = acc[mi][ni][r] + C[o];   // h holds the residual
            }
        }
    }
}

// ---------------------------------------------------------------- xproj MFMA: partials, split-K (3-buffer ring)
__global__ __launch_bounds__(256) void gemm_xproj(const __hip_bfloat16* __restrict__ A,
                                                  const __hip_bfloat16* __restrict__ W,
                                                  float* __restrict__ P) {
    __shared__ __align__(16) __hip_bfloat16 As[3][64*64];
    __shared__ __align__(16) __hip_bfloat16 Bs[3][96*64];
    int tid = threadIdx.x, lane = tid & 63, w = tid >> 6;
    int m0 = blockIdx.x * 64;
    int k0 = blockIdx.y * (D_INNER / KSPLIT);
    int kq = lane >> 4, rr = lane & 15;
    const int NK = (D_INNER/KSPLIT)/64;       // 6
    f32x4 acc[5];
    #pragma unroll
    for (int i = 0; i < 5; i++) acc[i] = (f32x4){0.f,0.f,0.f,0.f};
    const char* Ab = (const char*)A;
    const char* Wb = (const char*)W;
    char* AsB = (char*)As;
    char* BsB = (char*)Bs;

    auto stage = [&](int buf, int it) {
        int kk = k0 + it*64;
        #pragma unroll
        for (int cA = 0; cA < 2; cA++) {
            int idx = cA*256 + tid;
            int r = idx >> 3, q = (idx & 7) ^ (r & 7);
            glds16(Ab + ((size_t)(m0+r)*D_INNER + kk + q*8)*2, AsB + buf*8192 + idx*16);
        }
        #pragma unroll
        for (int cB = 0; cB < 3; cB++) {
            int idx = cB*256 + tid;
            int r = idx >> 3, q = (idx & 7) ^ (r & 7);
            int rs = r < XN ? r : XN-1;
            glds16(Wb + ((size_t)rs*D_INNER + kk + q*8)*2, BsB + buf*12288 + idx*16);
        }
    };

    stage(0, 0);
    stage(1, 1);

    for (int it = 0; it < NK; it++) {
        int cur = it % 3;
        __builtin_amdgcn_s_barrier();
        if (it + 2 < NK) stage((it + 2) % 3, it + 2);
        if (it + 2 < NK)      asm volatile("s_waitcnt vmcnt(10)" ::: "memory");
        else if (it + 1 < NK) asm volatile("s_waitcnt vmcnt(5)" ::: "memory");
        else                  asm volatile("s_waitcnt vmcnt(0)" ::: "memory");
        __builtin_amdgcn_s_barrier();
        #pragma unroll
        for (int kh = 0; kh < 2; kh++) {
            bf16x8 a = *(const bf16x8*)(AsB + cur*8192 + (w*16 + rr)*128 + (((kh*4 + kq) ^ (rr & 7)))*16);
            #pragma unroll
            for (int ni = 0; ni < 5; ni++) {
                bf16x8 b = *(const bf16x8*)(BsB + cur*12288 + (ni*16 + rr)*128 + (((kh*4 + kq) ^ (rr & 7)))*16);
                acc[ni] = __builtin_amdgcn_mfma_f32_16x16x32_bf16(a, b, acc[ni], 0, 0, 0);
            }
        }
    }
    float* Cp = P + (size_t)blockIdx.y * ROWS * XN;
    #pragma unroll
    for (int ni = 0; ni < 5; ni++)
        #pragma unroll
        for (int r = 0; r < 4; r++) {
            int row = m0 + w*16 + kq*4 + r;
            int col = ni*16 + rr;
            Cp[(size_t)row*XN + col] = acc[ni][r];
        }
}

// ---------------------------------------------------------------- depthwise causal conv + SiLU (bf16 in/out, x8 vec)
__global__ __launch_bounds__(256) void dwconv_silu(const __hip_bfloat16* __restrict__ xs,
                                                   const float* __restrict__ cw,
                                                   const float* __restrict__ cb,
                                                   __hip_bfloat16* __restrict__ u_bf) {
    int idx = blockIdx.x*256 + threadIdx.x;
    int dg = idx % (D_INNER/8);
    int t  = idx / (D_INNER/8);
    if (t >= ROWS) return;
    int d0 = dg*8;
    int l = t & 511, b = t >> 9;
    bf16x8 rows[K_CONV];
    #pragma unroll
    for (int k = 0; k < K_CONV; k++) {
        int ll = l - (K_CONV-1) + k;
        if (ll >= 0) rows[k] = *(const bf16x8*)(xs + ((size_t)(b*LSEQ + ll))*D_INNER + d0);
        else { bf16x8 z = {}; rows[k] = z; }
    }
    bf16x8 outv;
    #pragma unroll
    for (int j = 0; j < 8; j++) {
        int d = d0 + j;
        const float4 w4 = *(const float4*)(cw + d*K_CONV);
        float acc = cb[d]
                  + (float)rows[0][j]*w4.x + (float)rows[1][j]*w4.y
                  + (float)rows[2][j]*w4.z + (float)rows[3][j]*w4.w;
        float v = acc / (1.f + __expf(-acc));
        outv[j] = (__bf16)v;
    }
    *(bf16x8*)(u_bf + (size_t)t*D_INNER + d0) = outv;
}

// ---------------------------------------------------------------- selective scan, 3-phase chunked (NC=16, CL=32)
__global__ __launch_bounds__(256) void scan_p1(const __hip_bfloat16* __restrict__ u,
                                               const __hip_bfloat16* __restrict__ delta_blk,
                                               const float* __restrict__ xdbl,
                                               const float* __restrict__ A_log,
                                               float* __restrict__ xfin,
                                               float* __restrict__ sumdlt) {
    int d = blockIdx.x*256 + threadIdx.x;
    int c = blockIdx.y, b = blockIdx.z;
    int l0 = c*CL;
    const float* al = A_log + d*N_STATE;
    bool fast = true;
    #pragma unroll
    for (int n = 0; n < N_STATE; n++)
        fast = fast && (fabsf(__expf(al[n]) - (float)(n+1)) < 1e-3f);
    float xs[N_STATE];
    #pragma unroll
    for (int n = 0; n < N_STATE; n++) xs[n] = 0.f;
    const __hip_bfloat16* pu = u + (size_t)(b*LSEQ + l0)*D_INNER + d;
    const float* pB = xdbl + (size_t)(b*LSEQ + l0)*XN + DT_RANK;
    float sd = 0.f;
    if (fast) {
        #pragma unroll
        for (int tt = 0; tt < 2; tt++) {
            const __hip_bfloat16* db = delta_blk + ((size_t)(b*NTILE + (l0>>4) + tt)*D_INNER + d)*16;
            bf16x8 d0 = *(const bf16x8*)db;
            bf16x8 d1 = *(const bf16x8*)(db + 8);
            #pragma unroll
            for (int i = 0; i < 16; i++) {
                float dlt = (float)(i < 8 ? d0[i] : d1[i-8]);
                float uu = __bfloat162float(*pu); pu += D_INNER;
                float du = dlt*uu;
                sd += dlt;
                float e1 = fexp2(-dlt*LOG2E);
                float e = e1;
                xs[0] = e*xs[0] + du*pB[0];
                #pragma unroll
                for (int n = 1; n < N_STATE; n++) {
                    e *= e1;
                    xs[n] = e*xs[n] + du*pB[n];
                }
                pB += XN;
            }
        }
    } else {
        #pragma unroll
        for (int tt = 0; tt < 2; tt++) {
            const __hip_bfloat16* db = delta_blk + ((size_t)(b*NTILE + (l0>>4) + tt)*D_INNER + d)*16;
            bf16x8 d0 = *(const bf16x8*)db;
            bf16x8 d1 = *(const bf16x8*)(db + 8);
            #pragma unroll
            for (int i = 0; i < 16; i++) {
                float dlt = (float)(i < 8 ? d0[i] : d1[i-8]);
                float uu = __bfloat162float(*pu); pu += D_INNER;
                float du = dlt*uu;
                sd += dlt;
                #pragma unroll
                for (int n = 0; n < N_STATE; n++) {
                    float A2n = -__expf(al[n]) * LOG2E;
                    xs[n] = fexp2(dlt*A2n)*xs[n] + du*pB[n];
                }
                pB += XN;
            }
        }
    }
    float* px = xfin + (size_t)((b*NC + c)*N_STATE)*D_INNER + d;
    #pragma unroll
    for (int n = 0; n < N_STATE; n++) px[n*D_INNER] = xs[n];
    sumdlt[(size_t)(b*NC + c)*D_INNER + d] = sd;
}

__global__ __launch_bounds__(256) void scan_p2(float* __restrict__ xfin,
                                               const float* __restrict__ sumdlt,
                                               const float* __restrict__ A_log) {
    int idx = blockIdx.x*256 + threadIdx.x;
    int d = idx % D_INNER;
    int r = idx / D_INNER;
    int n = r & 15;
    int b = r >> 4;
    float A2 = -__expf(A_log[d*N_STATE + n]) * LOG2E;
    float cr = 0.f;
    for (int c = 1; c < NC; c++) {
        size_t jp = (size_t)(b*NC + c - 1);
        float xf = xfin[(jp*N_STATE + n)*D_INNER + d];
        float s  = sumdlt[jp*D_INNER + d];
        cr = fexp2(A2 * s) * cr + xf;
        xfin[(jp*N_STATE + n)*D_INNER + d] = cr;
    }
}

__global__ __launch_bounds__(256) void scan_p3(const __hip_bfloat16* __restrict__ u,
                                               const __hip_bfloat16* __restrict__ delta_blk,
                                               const __hip_bfloat16* __restrict__ gres,
                                               const float* __restrict__ xdbl,
                                               const float* __restrict__ A_log,
                                               const float* __restrict__ Dp,
                                               const float* __restrict__ carry,
                                               __hip_bfloat16* __restrict__ ygate) {
    int d = blockIdx.x*256 + threadIdx.x;
    int c = blockIdx.y, b = blockIdx.z;
    int l0 = c*CL;
    const float* al = A_log + d*N_STATE;
    bool fast = true;
    #pragma unroll
    for (int n = 0; n < N_STATE; n++)
        fast = fast && (fabsf(__expf(al[n]) - (float)(n+1)) < 1e-3f);
    float xs[N_STATE];
    if (c == 0) {
        #pragma unroll
        for (int n = 0; n < N_STATE; n++) xs[n] = 0.f;
    } else {
        const float* pc = carry + (size_t)((b*NC + c - 1)*N_STATE)*D_INNER + d;
        #pragma unroll
        for (int n = 0; n < N_STATE; n++) xs[n] = pc[n*D_INNER];
    }
    float Dv = Dp[d];
    const __hip_bfloat16* pu = u + (size_t)(b*LSEQ + l0)*D_INNER + d;
    const float* pB = xdbl + (size_t)(b*LSEQ + l0)*XN + DT_RANK;
    __hip_bfloat16* py = ygate + (size_t)(b*LSEQ + l0)*D_INNER + d;
    if (fast) {
        #pragma unroll
        for (int tt = 0; tt < 2; tt++) {
            size_t tb = (size_t)(b*NTILE + (l0>>4) + tt)*D_INNER + d;
            const __hip_bfloat16* db = delta_blk + tb*16;
            bf16x8 d0 = *(const bf16x8*)db;
            bf16x8 d1 = *(const bf16x8*)(db + 8);
            const __hip_bfloat16* gb = gres + tb*16;
            bf16x8 g0 = *(const bf16x8*)gb;
            bf16x8 g1 = *(const bf16x8*)(gb + 8);
            #pragma unroll
            for (int i = 0; i < 16; i++) {
                float dlt = (float)(i < 8 ? d0[i] : d1[i-8]);
                float gr  = (float)(i < 8 ? g0[i] : g1[i-8]);
                float uu = __bfloat162float(*pu); pu += D_INNER;
                float du = dlt*uu;
                float e1 = fexp2(-dlt*LOG2E);
                float e = e1;
                float acc;
                xs[0] = e*xs[0] + du*pB[0];
                acc = xs[0]*pB[N_STATE + 0];
                #pragma unroll
                for (int n = 1; n < N_STATE; n++) {
                    e *= e1;
                    xs[n] = e*xs[n] + du*pB[n];
                    acc += xs[n]*pB[N_STATE + n];
                }
                pB += XN;
                float y = acc + uu*Dv;
                *py = __float2bfloat16(y * gr); py += D_INNER;
            }
        }
    } else {
        #pragma unroll
        for (int tt = 0; tt < 2; tt++) {
            size_t tb = (size_t)(b*NTILE + (l0>>4) + tt)*D_INNER + d;
            const __hip_bfloat16* db = delta_blk + tb*16;
            bf16x8 d0 = *(const bf16x8*)db;
            bf16x8 d1 = *(const bf16x8*)(db + 8);
            const __hip_bfloat16* gb = gres + tb*16;
            bf16x8 g0 = *(const bf16x8*)gb;
            bf16x8 g1 = *(const bf16x8*)(gb + 8);
            #pragma unroll
            for (int i = 0; i < 16; i++) {
                float dlt = (float)(i < 8 ? d0[i] : d1[i-8]);
                float gr  = (float)(i < 8 ? g0[i] : g1[i-8]);
                float uu = __bfloat162float(*pu); pu += D_INNER;
                float du = dlt*uu;
                float acc = 0.f;
                #pragma unroll
                for (int n = 0; n < N_STATE; n++) {
                    float A2n = -__expf(al[n]) * LOG2E;
                    xs[n] = fexp2(dlt*A2n)*xs[n] + du*pB[n];
                    acc += xs[n]*pB[N_STATE + n];
                }
                pB += XN;
                float y = acc + uu*Dv;
                *py = __float2bfloat16(y * gr); py += D_INNER;
            }
        }
    }
}

// ---------------------------------------------------------------- final norm + head + de-norm
__global__ __launch_bounds__(256) void final_kernel(const float* __restrict__ h,
                                                    const float* __restrict__ fnw,
                                                    const float* __restrict__ out_w,
                                                    const float* __restrict__ mean,
                                                    const float* __restrict__ stdv,
                                                    float* __restrict__ out) {
    int bid = blockIdx.x;
    int b = bid / PRED_LEN, lo = bid % PRED_LEN;
    int l = LSEQ - PRED_LEN + lo;
    const float* row = h + ((size_t)(b*LSEQ + l))*D_MODEL;
    __shared__ float tmp[4];
    float ss = 0.f;
    for (int k = threadIdx.x; k < D_MODEL; k += 256) { float v = row[k]; ss += v*v; }
    ss = block_sum(ss, tmp);
    float inv = rsqrtf(ss / (float)D_MODEL + EPSV);
    float acc[C_OUT] = {};
    for (int k = threadIdx.x; k < D_MODEL; k += 256) {
        float hn = row[k]*fnw[k];
        #pragma unroll
        for (int c = 0; c < C_OUT; c++) acc[c] += hn*out_w[c*D_MODEL + k];
    }
    #pragma unroll
    for (int c = 0; c < C_OUT; c++) {
        float s = block_sum(acc[c], tmp);
        if (threadIdx.x == 0)
            out[((size_t)(b*PRED_LEN + lo))*C_OUT + c] = s*inv*stdv[b*ENC_IN + c] + mean[b*ENC_IN + c];
    }
}

// ---------------------------------------------------------------- launch
extern "C" void kernel_launch(void* const* d_in, const int* in_sizes, int n_in,
                              void* d_out, int out_size, void* d_ws, size_t ws_size,
                              hipStream_t stream) {
    const float* x        = (const float*)d_in[0];
    const float* token_w  = (const float*)d_in[1];
    const float* time_w   = (const float*)d_in[2];
    const float* norm_w   = (const float*)d_in[3];
    const float* in_w     = (const float*)d_in[4];
    const float* conv_w   = (const float*)d_in[5];
    const float* conv_b   = (const float*)d_in[6];
    const float* xproj_w  = (const float*)d_in[7];
    const float* dtproj_w = (const float*)d_in[8];
    const float* dtproj_b = (const float*)d_in[9];
    const float* A_log    = (const float*)d_in[10];
    const float* Dp       = (const float*)d_in[11];
    const float* outproj_w= (const float*)d_in[12];
    const float* final_nw = (const float*)d_in[13];
    const float* out_w    = (const float*)d_in[14];
    float* out = (float*)d_out;

    float* ws   = (float*)d_ws;
    float* mean = ws;
    float* stdv = ws + 64;
    float* h    = ws + 128;                            // ROWS*D_MODEL
    float* xdbl = h    + (size_t)ROWS*D_MODEL;         // ROWS*80 f32
    float* sumd = xdbl + (size_t)ROWS*XN;              // BSZ*NC*D_INNER
    float* xfin = sumd + (size_t)BSZ*NC*D_INNER;       // BSZ*NC*N_STATE*D_INNER
    float* pout = xfin + (size_t)BSZ*NC*D_INNER*N_STATE; // KSPLIT*ROWS*XN partials
    float* fend = pout + (size_t)KSPLIT*ROWS*XN;
    __hip_bfloat16* xn_bf  = (__hip_bfloat16*)fend;
    __hip_bfloat16* xs_bf  = xn_bf + (size_t)ROWS*D_MODEL;
    __hip_bfloat16* u_bf   = xs_bf + (size_t)ROWS*D_INNER;
    __hip_bfloat16* gres   = u_bf  + (size_t)ROWS*D_INNER;
    __hip_bfloat16* ygate  = gres  + (size_t)ROWS*D_INNER;
    __hip_bfloat16* delta  = ygate + (size_t)ROWS*D_INNER;
    __hip_bfloat16* inwp   = delta + (size_t)ROWS*D_INNER;           // packed in_w (frag-linear)
    __hip_bfloat16* outw_bf= inwp  + (size_t)E_LAYERS*INP_LAYER;
    __hip_bfloat16* xpw_bf = outw_bf+ (size_t)E_LAYERS*D_MODEL*D_INNER;
    __hip_bfloat16* dtw_bf = xpw_bf + (size_t)E_LAYERS*XN*D_INNER;

    {
        const int NT = E_LAYERS*D_MODEL*D_INNER + E_LAYERS*XN*D_INNER + E_LAYERS*D_INNER*64;
        cvt_all<<<(NT+255)/256, 256, 0, stream>>>(outproj_w, xproj_w, dtproj_w,
                                                  outw_bf, xpw_bf, dtw_bf);
        const int NP = E_LAYERS*INP_LAYER/8;
        pack_inw<<<(NP+255)/256, 256, 0, stream>>>(in_w, inwp);
    }

    stats_kernel<<<BSZ*ENC_IN, 256, 0, stream>>>(x, mean, stdv);
    embed_kernel<<<ROWS, 256, 0, stream>>>(x, token_w, time_w, mean, stdv, h);

    for (int e = 0; e < E_LAYERS; e++) {
        rmsnorm_bf16<<<ROWS, 256, 0, stream>>>(h, norm_w + e*D_MODEL, xn_bf);
        gemm_inproj<<<dim3(2*D_INNER/128, ROWS/128), 256, 0, stream>>>(
            xn_bf, inwp + (size_t)e*INP_LAYER, xs_bf, gres);
        dwconv_silu<<<(ROWS*(D_INNER/8) + 255)/256, 256, 0, stream>>>(
            xs_bf, conv_w + (size_t)e*D_INNER*K_CONV, conv_b + e*D_INNER, u_bf);
        gemm_xproj<<<dim3(ROWS/64, KSPLIT), 256, 0, stream>>>(
            u_bf, xpw_bf + (size_t)e*XN*D_INNER, pout);
        gemm_dtproj<<<dim3(D_INNER/128, ROWS/128), 256, 0, stream>>>(
            pout, dtw_bf + (size_t)e*D_INNER*64, dtproj_b + e*D_INNER, xdbl, delta);
        const float* Alog_e = A_log + (size_t)e*D_INNER*N_STATE;
        scan_p1<<<dim3(D_INNER/256, NC, BSZ), 256, 0, stream>>>(
            u_bf, delta, xdbl, Alog_e, xfin, sumd);
        scan_p2<<<(BSZ*D_INNER*N_STATE)/256, 256, 0, stream>>>(
            xfin, sumd, Alog_e);
        scan_p3<<<dim3(D_INNER/256, NC, BSZ), 256, 0, stream>>>(
            u_bf, delta, gres, xdbl, Alog_e, Dp + (size_t)e*D_INNER, xfin, ygate);
        gemm_outproj<<<dim3(D_MODEL/64, ROWS/128), 256, 0, stream>>>(
            ygate, outw_bf + (size_t)e*D_MODEL*D_INNER, h);
    }

    final_kernel<<<BSZ*PRED_LEN, 256, 0, stream>>>(h, final_nw, out_w, mean, stdv, out);
}